// Round 6
// baseline (483.148 us; speedup 1.0000x reference)
//
#include <hip/hip_runtime.h>

#define FEAT 128
#define N_CLS 10
#define CHUNK 16  // k-rows per staged W/Ws chunk

// ---------------- init: deg=1 (self loop), colsum=0 ----------------
__global__ void k_init(int* deg, float* colsum, int n) {
    int i = blockIdx.x * blockDim.x + threadIdx.x;
    if (i < n) deg[i] = 1;
    if (i < FEAT) colsum[i] = 0.f;
}

// ---------------- histogram of dst (int32 edge list) ----------------
__global__ void k_hist(const int* __restrict__ dst, int* deg, int E) {
    int e = blockIdx.x * blockDim.x + threadIdx.x;
    if (e < E) atomicAdd(&deg[dst[e]], 1);
}

// ---------------- hierarchical scan, stage 1: per-block sums of (deg-1) ----------------
__global__ __launch_bounds__(256) void k_bsum(const int* __restrict__ deg,
                                              int* __restrict__ bsum, int n) {
    int i = blockIdx.x * 256 + threadIdx.x;
    int v = (i < n) ? (deg[i] - 1) : 0;
    #pragma unroll
    for (int d = 32; d; d >>= 1) v += __shfl_down(v, d, 64);
    __shared__ int ws[4];
    int lane = threadIdx.x & 63, wid = threadIdx.x >> 6;
    if (lane == 0) ws[wid] = v;
    __syncthreads();
    if (threadIdx.x == 0) bsum[blockIdx.x] = ws[0] + ws[1] + ws[2] + ws[3];
}

// ---------------- stage 2: exclusive scan of block sums (nb <= 256) ----------------
__global__ __launch_bounds__(256) void k_bscan(int* bsum, int nb) {
    __shared__ int lds[256];
    int t = threadIdx.x;
    int v = (t < nb) ? bsum[t] : 0;
    lds[t] = v;
    __syncthreads();
    #pragma unroll
    for (int d = 1; d < 256; d <<= 1) {
        int u = (t >= d) ? lds[t - d] : 0;
        __syncthreads();
        lds[t] += u;
        __syncthreads();
    }
    if (t < nb) bsum[t] = lds[t] - v;  // exclusive prefix
}

// ---------------- stage 3: block-local scan + offset -> off/cursor/dinv ----------------
__global__ __launch_bounds__(256) void k_write(const int* __restrict__ deg,
                                               const int* __restrict__ bsum,
                                               int* off, int* cursor, float* dinv,
                                               int n, int E) {
    __shared__ int lds[256];
    int t = threadIdx.x;
    int i = blockIdx.x * 256 + t;
    int v = (i < n) ? (deg[i] - 1) : 0;
    lds[t] = v;
    __syncthreads();
    #pragma unroll
    for (int d = 1; d < 256; d <<= 1) {
        int u = (t >= d) ? lds[t - d] : 0;
        __syncthreads();
        lds[t] += u;
        __syncthreads();
    }
    if (i < n) {
        int o = bsum[blockIdx.x] + (lds[t] - v);
        off[i] = o;
        cursor[i] = o;
        dinv[i] = rsqrtf((float)deg[i]);
    }
    if (i == n - 1) off[n] = E;  // every edge lands in [0,n): total incoming == E
}

// ---------------- fill CSR (by dst), store src ----------------
__global__ void k_fill(const int* __restrict__ src, const int* __restrict__ dst,
                       int* cursor, int* csr, int E) {
    int e = blockIdx.x * blockDim.x + threadIdx.x;
    if (e < E) {
        int d = dst[e];
        int pos = atomicAdd(&cursor[d], 1);
        csr[pos] = src[e];
    }
}

// ---------------- fused dual GEMM: hs=(x@W)*dinv, xs=x@Ws+b+bs ----------------
// 32-row tile, 256 threads; W/Ws streamed through LDS in double-buffered
// CHUNK=16 k-chunks (prefetch to regs overlapped with compute; 1 barrier/chunk).
// Inner loop is all-LDS: W-read lane-consecutive ds_read_b128 (conflict-free),
// x-read 2-way broadcast (free). Per thread: 4 rows x (4 W-cols + 4 Ws-cols).
// NOTE: xs may alias x (in-place): block stages its 32 rows to LDS before
// any global write, and blocks only write their own rows.
__global__ __launch_bounds__(256) void k_gemm(
    const float* x, const float* __restrict__ W,
    const float* __restrict__ Ws, const float* __restrict__ b,
    const float* __restrict__ bs, const float* __restrict__ dinv,
    float* __restrict__ hs, float* xs, int n) {
    __shared__ float x_lds[32 * FEAT];          // 16 KB
    __shared__ float wst[2][2][CHUNK * FEAT];   // 32 KB: [buf][W|Ws][k][col]
    int tid = threadIdx.x;
    int row0 = blockIdx.x * 32;

    // stage x tile (coalesced float4)
    int c4 = (tid & 31) * 4;
    int rl = tid >> 5;  // 0..7
    #pragma unroll
    for (int p = 0; p < 4; ++p) {
        int r = rl + p * 8;
        float4 v = make_float4(0.f, 0.f, 0.f, 0.f);
        if (row0 + r < n) v = *(const float4*)&x[(size_t)(row0 + r) * FEAT + c4];
        *(float4*)&x_lds[r * FEAT + c4] = v;
    }

    // prefetch W/Ws chunk 0 (each chunk is a contiguous 8 KB = 512 float4)
    const float4* Wv = (const float4*)W;
    const float4* Sv = (const float4*)Ws;
    float4 pw[2], pv[2];
    #pragma unroll
    for (int q = 0; q < 2; ++q) {
        pw[q] = Wv[q * 256 + tid];
        pv[q] = Sv[q * 256 + tid];
    }
    #pragma unroll
    for (int q = 0; q < 2; ++q) {
        ((float4*)wst[0][0])[q * 256 + tid] = pw[q];
        ((float4*)wst[0][1])[q * 256 + tid] = pv[q];
    }
    __syncthreads();

    int ct = tid & 31;  // cols ct*4 .. ct*4+3
    int rt = tid >> 5;  // rows rt*4 .. rt*4+3
    float accW[4][4], accS[4][4];
    #pragma unroll
    for (int i = 0; i < 4; ++i)
        #pragma unroll
        for (int j = 0; j < 4; ++j) { accW[i][j] = 0.f; accS[i][j] = 0.f; }

    const int NCH = FEAT / CHUNK;  // 8
    for (int c = 0; c < NCH; ++c) {
        int cur = c & 1;
        if (c < NCH - 1) {  // issue next-chunk loads early (latency hides under FMAs)
            #pragma unroll
            for (int q = 0; q < 2; ++q) {
                pw[q] = Wv[(c + 1) * 512 + q * 256 + tid];
                pv[q] = Sv[(c + 1) * 512 + q * 256 + tid];
            }
        }
        const float* lw = wst[cur][0];
        const float* lv = wst[cur][1];
        #pragma unroll
        for (int k4 = 0; k4 < CHUNK / 4; ++k4) {
            float4 a[4];
            #pragma unroll
            for (int i = 0; i < 4; ++i)
                a[i] = *(const float4*)&x_lds[(rt * 4 + i) * FEAT + c * CHUNK + k4 * 4];
            #pragma unroll
            for (int kk = 0; kk < 4; ++kk) {
                float4 bw = *(const float4*)&lw[(k4 * 4 + kk) * FEAT + ct * 4];
                float4 bv = *(const float4*)&lv[(k4 * 4 + kk) * FEAT + ct * 4];
                #pragma unroll
                for (int i = 0; i < 4; ++i) {
                    float av = (&a[i].x)[kk];
                    accW[i][0] += av * bw.x; accW[i][1] += av * bw.y;
                    accW[i][2] += av * bw.z; accW[i][3] += av * bw.w;
                    accS[i][0] += av * bv.x; accS[i][1] += av * bv.y;
                    accS[i][2] += av * bv.z; accS[i][3] += av * bv.w;
                }
            }
        }
        if (c < NCH - 1) {  // write next chunk to the other buffer
            #pragma unroll
            for (int q = 0; q < 2; ++q) {
                ((float4*)wst[cur ^ 1][0])[q * 256 + tid] = pw[q];
                ((float4*)wst[cur ^ 1][1])[q * 256 + tid] = pv[q];
            }
        }
        __syncthreads();
    }

    float4 bb  = *(const float4*)&b[ct * 4];
    float4 bb2 = *(const float4*)&bs[ct * 4];
    float4 bias = make_float4(bb.x + bb2.x, bb.y + bb2.y, bb.z + bb2.z, bb.w + bb2.w);
    #pragma unroll
    for (int i = 0; i < 4; ++i) {
        int r = row0 + rt * 4 + i;
        if (r < n) {
            float dv = dinv[r];
            size_t o = (size_t)r * FEAT + ct * 4;
            float4 o1 = make_float4(accW[i][0] * dv, accW[i][1] * dv,
                                    accW[i][2] * dv, accW[i][3] * dv);
            *(float4*)&hs[o] = o1;
            float4 o2 = make_float4(accS[i][0] + bias.x, accS[i][1] + bias.y,
                                    accS[i][2] + bias.z, accS[i][3] + bias.w);
            *(float4*)&xs[o] = o2;
        }
    }
}

// ---------------- aggregation + skip + bias + relu (in place in xs) ----------------
// one wave per node, float2 per lane; 4-way unrolled gather for MLP
__global__ __launch_bounds__(256) void k_agg(
    const float* __restrict__ hs, float* __restrict__ xs,
    const float* __restrict__ dinv, const int* __restrict__ off,
    const int* __restrict__ csr, int n) {
    int wave = (blockIdx.x * 256 + threadIdx.x) >> 6;
    int lane = threadIdx.x & 63;
    if (wave >= n) return;
    int node = wave;
    size_t fo = (size_t)lane * 2;
    size_t o = (size_t)node * FEAT + fo;
    float2 a0 = *(const float2*)&hs[o];  // self loop contribution (pre-scaled)
    float2 a1 = make_float2(0.f, 0.f);
    float2 a2 = make_float2(0.f, 0.f);
    float2 a3 = make_float2(0.f, 0.f);
    int s = off[node], e = off[node + 1];
    int j = s;
    for (; j + 4 <= e; j += 4) {
        int u0 = csr[j], u1 = csr[j + 1], u2 = csr[j + 2], u3 = csr[j + 3];
        float2 v0 = *(const float2*)&hs[(size_t)u0 * FEAT + fo];
        float2 v1 = *(const float2*)&hs[(size_t)u1 * FEAT + fo];
        float2 v2 = *(const float2*)&hs[(size_t)u2 * FEAT + fo];
        float2 v3 = *(const float2*)&hs[(size_t)u3 * FEAT + fo];
        a0.x += v0.x; a0.y += v0.y;
        a1.x += v1.x; a1.y += v1.y;
        a2.x += v2.x; a2.y += v2.y;
        a3.x += v3.x; a3.y += v3.y;
    }
    for (; j < e; ++j) {
        int u = csr[j];
        float2 v = *(const float2*)&hs[(size_t)u * FEAT + fo];
        a0.x += v.x; a0.y += v.y;
    }
    float2 acc;
    acc.x = (a0.x + a1.x) + (a2.x + a3.x);
    acc.y = (a0.y + a1.y) + (a2.y + a3.y);
    float dv = dinv[node];
    float2 sk = *(const float2*)&xs[o];
    float2 out;
    out.x = fmaxf(fmaf(acc.x, dv, sk.x), 0.f);
    out.y = fmaxf(fmaf(acc.y, dv, sk.y), 0.f);
    *(float2*)&xs[o] = out;
}

// ---------------- column sum (block-reduced, atomics on 128 addrs) ----------------
__global__ __launch_bounds__(256) void k_colsum(const float* __restrict__ x2,
                                                float* colsum, int n) {
    __shared__ float lds[256];
    int tid = threadIdx.x;
    int f = tid & 127;
    int half = tid >> 7;
    float acc = 0.f;
    for (int r = blockIdx.x * 2 + half; r < n; r += gridDim.x * 2)
        acc += x2[(size_t)r * FEAT + f];
    lds[tid] = acc;
    __syncthreads();
    if (tid < 128) atomicAdd(&colsum[f], lds[f] + lds[f + 128]);
}

// ---------------- final: (colsum/n) @ Wc + bc ----------------
__global__ void k_final(const float* __restrict__ colsum, const float* __restrict__ Wc,
                        const float* __restrict__ bc, float* out, int n) {
    int c = threadIdx.x;
    if (c < N_CLS) {
        float acc = 0.f;
        for (int f = 0; f < FEAT; ++f) acc += colsum[f] * Wc[f * N_CLS + c];
        out[c] = acc / (float)n + bc[c];
    }
}

extern "C" void kernel_launch(void* const* d_in, const int* in_sizes, int n_in,
                              void* d_out, int out_size, void* d_ws, size_t ws_size,
                              hipStream_t stream) {
    const float* x   = (const float*)d_in[0];
    const int*   ei  = (const int*)d_in[1];   // harness passes integer inputs as int32
    const float* W1  = (const float*)d_in[2];
    const float* b1  = (const float*)d_in[3];
    const float* Ws1 = (const float*)d_in[4];
    const float* bs1 = (const float*)d_in[5];
    const float* W2  = (const float*)d_in[6];
    const float* b2  = (const float*)d_in[7];
    const float* Ws2 = (const float*)d_in[8];
    const float* bs2 = (const float*)d_in[9];
    const float* Wc  = (const float*)d_in[10];
    const float* bc  = (const float*)d_in[11];
    float* out = (float*)d_out;

    const int n = in_sizes[0] / FEAT;
    const int E = in_sizes[1] / 2;
    const int* src = ei;
    const int* dst = ei + E;

    const int nb = (n + 255) / 256;  // 196 blocks (<= 256 for k_bscan)

    // workspace carve-out (~55 MB total)
    char* w = (char*)d_ws;
    auto alloc = [&](size_t bytes) -> void* {
        void* p = (void*)w;
        w += (bytes + 255) & ~(size_t)255;
        return p;
    };
    int*   deg    = (int*)alloc((size_t)n * 4);
    int*   off    = (int*)alloc(((size_t)n + 1) * 4);
    int*   cursor = (int*)alloc((size_t)n * 4);
    int*   csr    = (int*)alloc((size_t)E * 4);
    float* dinv   = (float*)alloc((size_t)n * 4);
    float* colsum = (float*)alloc(FEAT * 4);
    int*   bsum   = (int*)alloc((size_t)nb * 4);
    float* A = (float*)alloc((size_t)n * FEAT * 4);  // hs (both layers)
    float* B = (float*)alloc((size_t)n * FEAT * 4);  // xs1 -> out1 -> xs2 -> out2

    // graph prep
    k_init<<<nb, 256, 0, stream>>>(deg, colsum, n);
    k_hist<<<(E + 255) / 256, 256, 0, stream>>>(dst, deg, E);
    k_bsum<<<nb, 256, 0, stream>>>(deg, bsum, n);
    k_bscan<<<1, 256, 0, stream>>>(bsum, nb);
    k_write<<<nb, 256, 0, stream>>>(deg, bsum, off, cursor, dinv, n, E);
    k_fill<<<(E + 255) / 256, 256, 0, stream>>>(src, dst, cursor, csr, E);

    int gemm_grid = (n + 31) / 32;
    int agg_grid  = (n + 3) / 4;

    // layer 1
    k_gemm<<<gemm_grid, 256, 0, stream>>>(x, W1, Ws1, b1, bs1, dinv, A, B, n);
    k_agg<<<agg_grid, 256, 0, stream>>>(A, B, dinv, off, csr, n);
    // layer 2 (xs written in-place into B; safe per-block row ownership)
    k_gemm<<<gemm_grid, 256, 0, stream>>>(B, W2, Ws2, b2, bs2, dinv, A, B, n);
    k_agg<<<agg_grid, 256, 0, stream>>>(A, B, dinv, off, csr, n);

    // readout
    k_colsum<<<512, 256, 0, stream>>>(B, colsum, n);
    k_final<<<1, 64, 0, stream>>>(colsum, Wc, bc, out, n);
}

// Round 7
// 441.465 us; speedup vs baseline: 1.0944x; 1.0944x over previous
//
#include <hip/hip_runtime.h>

#define FEAT 128
#define N_CLS 10

// ---------------- init: deg=1 (self loop), colsum=0 ----------------
__global__ void k_init(int* deg, float* colsum, int n) {
    int i = blockIdx.x * blockDim.x + threadIdx.x;
    if (i < n) deg[i] = 1;
    if (i < FEAT) colsum[i] = 0.f;
}

// ---------------- histogram of dst (int32 edge list) ----------------
__global__ void k_hist(const int* __restrict__ dst, int* deg, int E) {
    int e = blockIdx.x * blockDim.x + threadIdx.x;
    if (e < E) atomicAdd(&deg[dst[e]], 1);
}

// ---------------- hierarchical scan, stage 1: per-block sums of (deg-1) ----------------
__global__ __launch_bounds__(256) void k_bsum(const int* __restrict__ deg,
                                              int* __restrict__ bsum, int n) {
    int i = blockIdx.x * 256 + threadIdx.x;
    int v = (i < n) ? (deg[i] - 1) : 0;
    #pragma unroll
    for (int d = 32; d; d >>= 1) v += __shfl_down(v, d, 64);
    __shared__ int ws[4];
    int lane = threadIdx.x & 63, wid = threadIdx.x >> 6;
    if (lane == 0) ws[wid] = v;
    __syncthreads();
    if (threadIdx.x == 0) bsum[blockIdx.x] = ws[0] + ws[1] + ws[2] + ws[3];
}

// ---------------- stage 2: exclusive scan of block sums (nb <= 256) ----------------
__global__ __launch_bounds__(256) void k_bscan(int* bsum, int nb) {
    __shared__ int lds[256];
    int t = threadIdx.x;
    int v = (t < nb) ? bsum[t] : 0;
    lds[t] = v;
    __syncthreads();
    #pragma unroll
    for (int d = 1; d < 256; d <<= 1) {
        int u = (t >= d) ? lds[t - d] : 0;
        __syncthreads();
        lds[t] += u;
        __syncthreads();
    }
    if (t < nb) bsum[t] = lds[t] - v;  // exclusive prefix
}

// ---------------- stage 3: block-local scan + offset -> off/cursor/dinv ----------------
__global__ __launch_bounds__(256) void k_write(const int* __restrict__ deg,
                                               const int* __restrict__ bsum,
                                               int* off, int* cursor, float* dinv,
                                               int n, int E) {
    __shared__ int lds[256];
    int t = threadIdx.x;
    int i = blockIdx.x * 256 + t;
    int v = (i < n) ? (deg[i] - 1) : 0;
    lds[t] = v;
    __syncthreads();
    #pragma unroll
    for (int d = 1; d < 256; d <<= 1) {
        int u = (t >= d) ? lds[t - d] : 0;
        __syncthreads();
        lds[t] += u;
        __syncthreads();
    }
    if (i < n) {
        int o = bsum[blockIdx.x] + (lds[t] - v);
        off[i] = o;
        cursor[i] = o;
        dinv[i] = rsqrtf((float)deg[i]);
    }
    if (i == n - 1) off[n] = E;  // every edge lands in [0,n): total incoming == E
}

// ---------------- fill CSR (by dst), store src ----------------
__global__ void k_fill(const int* __restrict__ src, const int* __restrict__ dst,
                       int* cursor, int* csr, int E) {
    int e = blockIdx.x * blockDim.x + threadIdx.x;
    if (e < E) {
        int d = dst[e];
        int pos = atomicAdd(&cursor[d], 1);
        csr[pos] = src[e];
    }
}

// ---------------- split dual GEMM ----------------
// Block pair = blockIdx.x>>1 covers 64 rows; which = blockIdx.x&1 selects:
//   which==0: hs = (x@W)*dinv[row]        which==1: xs = x@Ws + (b+bs)
// Per thread: 8 rows x 4 cols of ONE matrix (32 accs). W rows from global
// (L2-resident, wave footprint 512B); x tile in LDS (2-way broadcast reads).
__global__ __launch_bounds__(256) void k_gemm(
    const float* __restrict__ x, const float* __restrict__ W,
    const float* __restrict__ Ws, const float* __restrict__ b,
    const float* __restrict__ bs, const float* __restrict__ dinv,
    float* __restrict__ hs, float* __restrict__ xs, int n) {
    __shared__ float x_lds[64 * FEAT];  // 32 KB
    int tid = threadIdx.x;
    int pair = blockIdx.x >> 1;
    int which = blockIdx.x & 1;
    int row0 = pair * 64;

    // stage x tile (coalesced float4)
    int c4 = (tid & 31) * 4;
    int rl = tid >> 5;  // 0..7
    #pragma unroll
    for (int p = 0; p < 8; ++p) {
        int r = rl + p * 8;
        float4 v = make_float4(0.f, 0.f, 0.f, 0.f);
        if (row0 + r < n) v = *(const float4*)&x[(size_t)(row0 + r) * FEAT + c4];
        *(float4*)&x_lds[r * FEAT + c4] = v;
    }
    __syncthreads();

    int ct = tid & 31;  // cols ct*4 .. ct*4+3
    int rt = tid >> 5;  // rows rt*8 .. rt*8+7
    float acc[8][4];
    #pragma unroll
    for (int i = 0; i < 8; ++i)
        #pragma unroll
        for (int j = 0; j < 4; ++j) acc[i][j] = 0.f;

    const float4* Mv = (const float4*)(which ? Ws : W) + ct;  // row k at Mv[k*32]
    for (int k = 0; k < FEAT; k += 4) {
        float4 b0 = Mv[(size_t)(k + 0) * 32];
        float4 b1 = Mv[(size_t)(k + 1) * 32];
        float4 b2 = Mv[(size_t)(k + 2) * 32];
        float4 b3 = Mv[(size_t)(k + 3) * 32];
        #pragma unroll
        for (int i = 0; i < 8; ++i) {
            float4 a = *(const float4*)&x_lds[(rt * 8 + i) * FEAT + k];
            acc[i][0] += a.x * b0.x; acc[i][1] += a.x * b0.y;
            acc[i][2] += a.x * b0.z; acc[i][3] += a.x * b0.w;
            acc[i][0] += a.y * b1.x; acc[i][1] += a.y * b1.y;
            acc[i][2] += a.y * b1.z; acc[i][3] += a.y * b1.w;
            acc[i][0] += a.z * b2.x; acc[i][1] += a.z * b2.y;
            acc[i][2] += a.z * b2.z; acc[i][3] += a.z * b2.w;
            acc[i][0] += a.w * b3.x; acc[i][1] += a.w * b3.y;
            acc[i][2] += a.w * b3.z; acc[i][3] += a.w * b3.w;
        }
    }

    if (which == 0) {
        #pragma unroll
        for (int i = 0; i < 8; ++i) {
            int r = row0 + rt * 8 + i;
            if (r < n) {
                float dv = dinv[r];
                size_t o = (size_t)r * FEAT + ct * 4;
                *(float4*)&hs[o] = make_float4(acc[i][0] * dv, acc[i][1] * dv,
                                               acc[i][2] * dv, acc[i][3] * dv);
            }
        }
    } else {
        float4 bb  = *(const float4*)&b[ct * 4];
        float4 bb2 = *(const float4*)&bs[ct * 4];
        float4 bias = make_float4(bb.x + bb2.x, bb.y + bb2.y, bb.z + bb2.z, bb.w + bb2.w);
        #pragma unroll
        for (int i = 0; i < 8; ++i) {
            int r = row0 + rt * 8 + i;
            if (r < n) {
                size_t o = (size_t)r * FEAT + ct * 4;
                *(float4*)&xs[o] = make_float4(acc[i][0] + bias.x, acc[i][1] + bias.y,
                                               acc[i][2] + bias.z, acc[i][3] + bias.w);
            }
        }
    }
}

// ---------------- aggregation + skip + bias + relu (in place in xs) ----------------
// one wave per node, float2 per lane; 4-way unrolled gather for MLP
__global__ __launch_bounds__(256) void k_agg(
    const float* __restrict__ hs, float* __restrict__ xs,
    const float* __restrict__ dinv, const int* __restrict__ off,
    const int* __restrict__ csr, int n) {
    int wave = (blockIdx.x * 256 + threadIdx.x) >> 6;
    int lane = threadIdx.x & 63;
    if (wave >= n) return;
    int node = wave;
    size_t fo = (size_t)lane * 2;
    size_t o = (size_t)node * FEAT + fo;
    float2 a0 = *(const float2*)&hs[o];  // self loop contribution (pre-scaled)
    float2 a1 = make_float2(0.f, 0.f);
    float2 a2 = make_float2(0.f, 0.f);
    float2 a3 = make_float2(0.f, 0.f);
    int s = off[node], e = off[node + 1];
    int j = s;
    for (; j + 4 <= e; j += 4) {
        int u0 = csr[j], u1 = csr[j + 1], u2 = csr[j + 2], u3 = csr[j + 3];
        float2 v0 = *(const float2*)&hs[(size_t)u0 * FEAT + fo];
        float2 v1 = *(const float2*)&hs[(size_t)u1 * FEAT + fo];
        float2 v2 = *(const float2*)&hs[(size_t)u2 * FEAT + fo];
        float2 v3 = *(const float2*)&hs[(size_t)u3 * FEAT + fo];
        a0.x += v0.x; a0.y += v0.y;
        a1.x += v1.x; a1.y += v1.y;
        a2.x += v2.x; a2.y += v2.y;
        a3.x += v3.x; a3.y += v3.y;
    }
    for (; j < e; ++j) {
        int u = csr[j];
        float2 v = *(const float2*)&hs[(size_t)u * FEAT + fo];
        a0.x += v.x; a0.y += v.y;
    }
    float2 acc;
    acc.x = (a0.x + a1.x) + (a2.x + a3.x);
    acc.y = (a0.y + a1.y) + (a2.y + a3.y);
    float dv = dinv[node];
    float2 sk = *(const float2*)&xs[o];
    float2 out;
    out.x = fmaxf(fmaf(acc.x, dv, sk.x), 0.f);
    out.y = fmaxf(fmaf(acc.y, dv, sk.y), 0.f);
    *(float2*)&xs[o] = out;
}

// ---------------- column sum (block-reduced, atomics on 128 addrs) ----------------
__global__ __launch_bounds__(256) void k_colsum(const float* __restrict__ x2,
                                                float* colsum, int n) {
    __shared__ float lds[256];
    int tid = threadIdx.x;
    int f = tid & 127;
    int half = tid >> 7;
    float acc = 0.f;
    for (int r = blockIdx.x * 2 + half; r < n; r += gridDim.x * 2)
        acc += x2[(size_t)r * FEAT + f];
    lds[tid] = acc;
    __syncthreads();
    if (tid < 128) atomicAdd(&colsum[f], lds[f] + lds[f + 128]);
}

// ---------------- final: (colsum/n) @ Wc + bc ----------------
__global__ void k_final(const float* __restrict__ colsum, const float* __restrict__ Wc,
                        const float* __restrict__ bc, float* out, int n) {
    int c = threadIdx.x;
    if (c < N_CLS) {
        float acc = 0.f;
        for (int f = 0; f < FEAT; ++f) acc += colsum[f] * Wc[f * N_CLS + c];
        out[c] = acc / (float)n + bc[c];
    }
}

extern "C" void kernel_launch(void* const* d_in, const int* in_sizes, int n_in,
                              void* d_out, int out_size, void* d_ws, size_t ws_size,
                              hipStream_t stream) {
    const float* x   = (const float*)d_in[0];
    const int*   ei  = (const int*)d_in[1];   // harness passes integer inputs as int32
    const float* W1  = (const float*)d_in[2];
    const float* b1  = (const float*)d_in[3];
    const float* Ws1 = (const float*)d_in[4];
    const float* bs1 = (const float*)d_in[5];
    const float* W2  = (const float*)d_in[6];
    const float* b2  = (const float*)d_in[7];
    const float* Ws2 = (const float*)d_in[8];
    const float* bs2 = (const float*)d_in[9];
    const float* Wc  = (const float*)d_in[10];
    const float* bc  = (const float*)d_in[11];
    float* out = (float*)d_out;

    const int n = in_sizes[0] / FEAT;
    const int E = in_sizes[1] / 2;
    const int* src = ei;
    const int* dst = ei + E;

    const int nb = (n + 255) / 256;  // 196 blocks (<= 256 for k_bscan)

    // workspace carve-out (~81 MB total; R3 confirmed this fits ws)
    char* w = (char*)d_ws;
    auto alloc = [&](size_t bytes) -> void* {
        void* p = (void*)w;
        w += (bytes + 255) & ~(size_t)255;
        return p;
    };
    int*   deg    = (int*)alloc((size_t)n * 4);
    int*   off    = (int*)alloc(((size_t)n + 1) * 4);
    int*   cursor = (int*)alloc((size_t)n * 4);
    int*   csr    = (int*)alloc((size_t)E * 4);
    float* dinv   = (float*)alloc((size_t)n * 4);
    float* colsum = (float*)alloc(FEAT * 4);
    int*   bsum   = (int*)alloc((size_t)nb * 4);
    float* A = (float*)alloc((size_t)n * FEAT * 4);  // hs (both layers)
    float* B = (float*)alloc((size_t)n * FEAT * 4);  // xs1 -> out1 (layer-2 input)
    float* C = (float*)alloc((size_t)n * FEAT * 4);  // xs2 -> out2 (no aliasing w/ split gemm)

    // graph prep
    k_init<<<nb, 256, 0, stream>>>(deg, colsum, n);
    k_hist<<<(E + 255) / 256, 256, 0, stream>>>(dst, deg, E);
    k_bsum<<<nb, 256, 0, stream>>>(deg, bsum, n);
    k_bscan<<<1, 256, 0, stream>>>(bsum, nb);
    k_write<<<nb, 256, 0, stream>>>(deg, bsum, off, cursor, dinv, n, E);
    k_fill<<<(E + 255) / 256, 256, 0, stream>>>(src, dst, cursor, csr, E);

    int gemm_grid = 2 * ((n + 63) / 64);  // pairs x {W-half, Ws-half}
    int agg_grid  = (n + 3) / 4;

    // layer 1
    k_gemm<<<gemm_grid, 256, 0, stream>>>(x, W1, Ws1, b1, bs1, dinv, A, B, n);
    k_agg<<<agg_grid, 256, 0, stream>>>(A, B, dinv, off, csr, n);
    // layer 2 (separate output buffer C: split blocks must not write their input)
    k_gemm<<<gemm_grid, 256, 0, stream>>>(B, W2, Ws2, b2, bs2, dinv, A, C, n);
    k_agg<<<agg_grid, 256, 0, stream>>>(A, C, dinv, off, csr, n);

    // readout
    k_colsum<<<512, 256, 0, stream>>>(C, colsum, n);
    k_final<<<1, 64, 0, stream>>>(colsum, Wc, bc, out, n);
}

// Round 8
// 426.578 us; speedup vs baseline: 1.1326x; 1.0349x over previous
//
#include <hip/hip_runtime.h>

#define FEAT 128
#define N_CLS 10

// ---------------- init: deg=1 (self loop), colsum=0 ----------------
__global__ void k_init(int* deg, float* colsum, int n) {
    int i = blockIdx.x * blockDim.x + threadIdx.x;
    if (i < n) deg[i] = 1;
    if (i < FEAT) colsum[i] = 0.f;
}

// ---------------- histogram of dst (int32 edge list) ----------------
__global__ void k_hist(const int* __restrict__ dst, int* deg, int E) {
    int e = blockIdx.x * blockDim.x + threadIdx.x;
    if (e < E) atomicAdd(&deg[dst[e]], 1);
}

// ---------------- hierarchical scan, stage 1: per-block sums of (deg-1) ----------------
__global__ __launch_bounds__(256) void k_bsum(const int* __restrict__ deg,
                                              int* __restrict__ bsum, int n) {
    int i = blockIdx.x * 256 + threadIdx.x;
    int v = (i < n) ? (deg[i] - 1) : 0;
    #pragma unroll
    for (int d = 32; d; d >>= 1) v += __shfl_down(v, d, 64);
    __shared__ int ws[4];
    int lane = threadIdx.x & 63, wid = threadIdx.x >> 6;
    if (lane == 0) ws[wid] = v;
    __syncthreads();
    if (threadIdx.x == 0) bsum[blockIdx.x] = ws[0] + ws[1] + ws[2] + ws[3];
}

// ---------------- stage 2: exclusive scan of block sums (nb <= 256) ----------------
__global__ __launch_bounds__(256) void k_bscan(int* bsum, int nb) {
    __shared__ int lds[256];
    int t = threadIdx.x;
    int v = (t < nb) ? bsum[t] : 0;
    lds[t] = v;
    __syncthreads();
    #pragma unroll
    for (int d = 1; d < 256; d <<= 1) {
        int u = (t >= d) ? lds[t - d] : 0;
        __syncthreads();
        lds[t] += u;
        __syncthreads();
    }
    if (t < nb) bsum[t] = lds[t] - v;  // exclusive prefix
}

// ---------------- stage 3: block-local scan + offset -> off/cursor/dinv ----------------
__global__ __launch_bounds__(256) void k_write(const int* __restrict__ deg,
                                               const int* __restrict__ bsum,
                                               int* off, int* cursor, float* dinv,
                                               int n, int E) {
    __shared__ int lds[256];
    int t = threadIdx.x;
    int i = blockIdx.x * 256 + t;
    int v = (i < n) ? (deg[i] - 1) : 0;
    lds[t] = v;
    __syncthreads();
    #pragma unroll
    for (int d = 1; d < 256; d <<= 1) {
        int u = (t >= d) ? lds[t - d] : 0;
        __syncthreads();
        lds[t] += u;
        __syncthreads();
    }
    if (i < n) {
        int o = bsum[blockIdx.x] + (lds[t] - v);
        off[i] = o;
        cursor[i] = o;
        dinv[i] = rsqrtf((float)deg[i]);
    }
    if (i == n - 1) off[n] = E;  // every edge lands in [0,n): total incoming == E
}

// ---------------- fill CSR (by dst), store src ----------------
__global__ void k_fill(const int* __restrict__ src, const int* __restrict__ dst,
                       int* cursor, int* csr, int E) {
    int e = blockIdx.x * blockDim.x + threadIdx.x;
    if (e < E) {
        int d = dst[e];
        int pos = atomicAdd(&cursor[d], 1);
        csr[pos] = src[e];
    }
}

// ---------------- split dual GEMM ----------------
// Block pair = blockIdx.x>>1 covers 64 rows; which = blockIdx.x&1 selects:
//   which==0: hs = (x@W)*dinv[row]        which==1: xs = x@Ws + (b+bs)
// Per thread: 8 rows x 4 cols of ONE matrix (32 accs). W rows from global
// (L2-resident, wave footprint 512B); x tile in LDS (2-way broadcast reads).
__global__ __launch_bounds__(256) void k_gemm(
    const float* __restrict__ x, const float* __restrict__ W,
    const float* __restrict__ Ws, const float* __restrict__ b,
    const float* __restrict__ bs, const float* __restrict__ dinv,
    float* __restrict__ hs, float* __restrict__ xs, int n) {
    __shared__ float x_lds[64 * FEAT];  // 32 KB
    int tid = threadIdx.x;
    int pair = blockIdx.x >> 1;
    int which = blockIdx.x & 1;
    int row0 = pair * 64;

    // stage x tile (coalesced float4)
    int c4 = (tid & 31) * 4;
    int rl = tid >> 5;  // 0..7
    #pragma unroll
    for (int p = 0; p < 8; ++p) {
        int r = rl + p * 8;
        float4 v = make_float4(0.f, 0.f, 0.f, 0.f);
        if (row0 + r < n) v = *(const float4*)&x[(size_t)(row0 + r) * FEAT + c4];
        *(float4*)&x_lds[r * FEAT + c4] = v;
    }
    __syncthreads();

    int ct = tid & 31;  // cols ct*4 .. ct*4+3
    int rt = tid >> 5;  // rows rt*8 .. rt*8+7
    float acc[8][4];
    #pragma unroll
    for (int i = 0; i < 8; ++i)
        #pragma unroll
        for (int j = 0; j < 4; ++j) acc[i][j] = 0.f;

    const float4* Mv = (const float4*)(which ? Ws : W) + ct;  // row k at Mv[k*32]
    for (int k = 0; k < FEAT; k += 4) {
        float4 b0 = Mv[(size_t)(k + 0) * 32];
        float4 b1 = Mv[(size_t)(k + 1) * 32];
        float4 b2 = Mv[(size_t)(k + 2) * 32];
        float4 b3 = Mv[(size_t)(k + 3) * 32];
        #pragma unroll
        for (int i = 0; i < 8; ++i) {
            float4 a = *(const float4*)&x_lds[(rt * 8 + i) * FEAT + k];
            acc[i][0] += a.x * b0.x; acc[i][1] += a.x * b0.y;
            acc[i][2] += a.x * b0.z; acc[i][3] += a.x * b0.w;
            acc[i][0] += a.y * b1.x; acc[i][1] += a.y * b1.y;
            acc[i][2] += a.y * b1.z; acc[i][3] += a.y * b1.w;
            acc[i][0] += a.z * b2.x; acc[i][1] += a.z * b2.y;
            acc[i][2] += a.z * b2.z; acc[i][3] += a.z * b2.w;
            acc[i][0] += a.w * b3.x; acc[i][1] += a.w * b3.y;
            acc[i][2] += a.w * b3.z; acc[i][3] += a.w * b3.w;
        }
    }

    if (which == 0) {
        #pragma unroll
        for (int i = 0; i < 8; ++i) {
            int r = row0 + rt * 8 + i;
            if (r < n) {
                float dv = dinv[r];
                size_t o = (size_t)r * FEAT + ct * 4;
                *(float4*)&hs[o] = make_float4(acc[i][0] * dv, acc[i][1] * dv,
                                               acc[i][2] * dv, acc[i][3] * dv);
            }
        }
    } else {
        float4 bb  = *(const float4*)&b[ct * 4];
        float4 bb2 = *(const float4*)&bs[ct * 4];
        float4 bias = make_float4(bb.x + bb2.x, bb.y + bb2.y, bb.z + bb2.z, bb.w + bb2.w);
        #pragma unroll
        for (int i = 0; i < 8; ++i) {
            int r = row0 + rt * 8 + i;
            if (r < n) {
                size_t o = (size_t)r * FEAT + ct * 4;
                *(float4*)&xs[o] = make_float4(acc[i][0] + bias.x, acc[i][1] + bias.y,
                                               acc[i][2] + bias.z, acc[i][3] + bias.w);
            }
        }
    }
}

// ---------------- aggregation + skip + bias + relu (in place in xs) ----------------
// ONE NODE PER 32-LANE HALF-WAVE, float4 per lane: one dwordx4 instruction
// gathers a full 512B row; 4-way unroll -> 8 rows in flight per wave.
__global__ __launch_bounds__(256) void k_agg(
    const float* __restrict__ hs, float* __restrict__ xs,
    const float* __restrict__ dinv, const int* __restrict__ off,
    const int* __restrict__ csr, int n) {
    int node = (blockIdx.x * 256 + threadIdx.x) >> 5;
    int sub = threadIdx.x & 31;
    if (node >= n) return;
    size_t fo = (size_t)sub * 4;
    size_t o = (size_t)node * FEAT + fo;
    float4 a0 = *(const float4*)&hs[o];  // self loop contribution (pre-scaled)
    float4 a1 = make_float4(0.f, 0.f, 0.f, 0.f);
    float4 a2 = make_float4(0.f, 0.f, 0.f, 0.f);
    float4 a3 = make_float4(0.f, 0.f, 0.f, 0.f);
    int s = off[node], e = off[node + 1];
    int j = s;
    for (; j + 4 <= e; j += 4) {
        int u0 = csr[j], u1 = csr[j + 1], u2 = csr[j + 2], u3 = csr[j + 3];
        float4 v0 = *(const float4*)&hs[(size_t)u0 * FEAT + fo];
        float4 v1 = *(const float4*)&hs[(size_t)u1 * FEAT + fo];
        float4 v2 = *(const float4*)&hs[(size_t)u2 * FEAT + fo];
        float4 v3 = *(const float4*)&hs[(size_t)u3 * FEAT + fo];
        a0.x += v0.x; a0.y += v0.y; a0.z += v0.z; a0.w += v0.w;
        a1.x += v1.x; a1.y += v1.y; a1.z += v1.z; a1.w += v1.w;
        a2.x += v2.x; a2.y += v2.y; a2.z += v2.z; a2.w += v2.w;
        a3.x += v3.x; a3.y += v3.y; a3.z += v3.z; a3.w += v3.w;
    }
    for (; j < e; ++j) {
        int u = csr[j];
        float4 v = *(const float4*)&hs[(size_t)u * FEAT + fo];
        a0.x += v.x; a0.y += v.y; a0.z += v.z; a0.w += v.w;
    }
    float4 acc;
    acc.x = (a0.x + a1.x) + (a2.x + a3.x);
    acc.y = (a0.y + a1.y) + (a2.y + a3.y);
    acc.z = (a0.z + a1.z) + (a2.z + a3.z);
    acc.w = (a0.w + a1.w) + (a2.w + a3.w);
    float dv = dinv[node];
    float4 sk = *(const float4*)&xs[o];
    float4 out;
    out.x = fmaxf(fmaf(acc.x, dv, sk.x), 0.f);
    out.y = fmaxf(fmaf(acc.y, dv, sk.y), 0.f);
    out.z = fmaxf(fmaf(acc.z, dv, sk.z), 0.f);
    out.w = fmaxf(fmaf(acc.w, dv, sk.w), 0.f);
    *(float4*)&xs[o] = out;
}

// ---------------- column sum (block-reduced, atomics on 128 addrs) ----------------
__global__ __launch_bounds__(256) void k_colsum(const float* __restrict__ x2,
                                                float* colsum, int n) {
    __shared__ float lds[256];
    int tid = threadIdx.x;
    int f = tid & 127;
    int half = tid >> 7;
    float acc = 0.f;
    for (int r = blockIdx.x * 2 + half; r < n; r += gridDim.x * 2)
        acc += x2[(size_t)r * FEAT + f];
    lds[tid] = acc;
    __syncthreads();
    if (tid < 128) atomicAdd(&colsum[f], lds[f] + lds[f + 128]);
}

// ---------------- final: (colsum/n) @ Wc + bc ----------------
__global__ void k_final(const float* __restrict__ colsum, const float* __restrict__ Wc,
                        const float* __restrict__ bc, float* out, int n) {
    int c = threadIdx.x;
    if (c < N_CLS) {
        float acc = 0.f;
        for (int f = 0; f < FEAT; ++f) acc += colsum[f] * Wc[f * N_CLS + c];
        out[c] = acc / (float)n + bc[c];
    }
}

extern "C" void kernel_launch(void* const* d_in, const int* in_sizes, int n_in,
                              void* d_out, int out_size, void* d_ws, size_t ws_size,
                              hipStream_t stream) {
    const float* x   = (const float*)d_in[0];
    const int*   ei  = (const int*)d_in[1];   // harness passes integer inputs as int32
    const float* W1  = (const float*)d_in[2];
    const float* b1  = (const float*)d_in[3];
    const float* Ws1 = (const float*)d_in[4];
    const float* bs1 = (const float*)d_in[5];
    const float* W2  = (const float*)d_in[6];
    const float* b2  = (const float*)d_in[7];
    const float* Ws2 = (const float*)d_in[8];
    const float* bs2 = (const float*)d_in[9];
    const float* Wc  = (const float*)d_in[10];
    const float* bc  = (const float*)d_in[11];
    float* out = (float*)d_out;

    const int n = in_sizes[0] / FEAT;
    const int E = in_sizes[1] / 2;
    const int* src = ei;
    const int* dst = ei + E;

    const int nb = (n + 255) / 256;  // 196 blocks (<= 256 for k_bscan)

    // workspace carve-out (~81 MB total; R3 confirmed this fits ws)
    char* w = (char*)d_ws;
    auto alloc = [&](size_t bytes) -> void* {
        void* p = (void*)w;
        w += (bytes + 255) & ~(size_t)255;
        return p;
    };
    int*   deg    = (int*)alloc((size_t)n * 4);
    int*   off    = (int*)alloc(((size_t)n + 1) * 4);
    int*   cursor = (int*)alloc((size_t)n * 4);
    int*   csr    = (int*)alloc((size_t)E * 4);
    float* dinv   = (float*)alloc((size_t)n * 4);
    float* colsum = (float*)alloc(FEAT * 4);
    int*   bsum   = (int*)alloc((size_t)nb * 4);
    float* A = (float*)alloc((size_t)n * FEAT * 4);  // hs (both layers)
    float* B = (float*)alloc((size_t)n * FEAT * 4);  // xs1 -> out1 (layer-2 input)
    float* C = (float*)alloc((size_t)n * FEAT * 4);  // xs2 -> out2 (no aliasing w/ split gemm)

    // graph prep
    k_init<<<nb, 256, 0, stream>>>(deg, colsum, n);
    k_hist<<<(E + 255) / 256, 256, 0, stream>>>(dst, deg, E);
    k_bsum<<<nb, 256, 0, stream>>>(deg, bsum, n);
    k_bscan<<<1, 256, 0, stream>>>(bsum, nb);
    k_write<<<nb, 256, 0, stream>>>(deg, bsum, off, cursor, dinv, n, E);
    k_fill<<<(E + 255) / 256, 256, 0, stream>>>(src, dst, cursor, csr, E);

    int gemm_grid = 2 * ((n + 63) / 64);  // pairs x {W-half, Ws-half}
    int agg_grid  = (n + 7) / 8;          // one node per 32-lane half-wave

    // layer 1
    k_gemm<<<gemm_grid, 256, 0, stream>>>(x, W1, Ws1, b1, bs1, dinv, A, B, n);
    k_agg<<<agg_grid, 256, 0, stream>>>(A, B, dinv, off, csr, n);
    // layer 2 (separate output buffer C: split blocks must not write their input)
    k_gemm<<<gemm_grid, 256, 0, stream>>>(B, W2, Ws2, b2, bs2, dinv, A, C, n);
    k_agg<<<agg_grid, 256, 0, stream>>>(A, C, dinv, off, csr, n);

    // readout
    k_colsum<<<512, 256, 0, stream>>>(C, colsum, n);
    k_final<<<1, 64, 0, stream>>>(colsum, Wc, bc, out, n);
}

// Round 9
// 390.989 us; speedup vs baseline: 1.2357x; 1.0910x over previous
//
#include <hip/hip_runtime.h>

#define FEAT 128
#define N_CLS 10

typedef unsigned int uint;

// ---- bf16 helpers (manual, RNE pack / exact unpack) ----
__device__ inline unsigned short f2bf(float f) {
    union { float f; uint u; } c; c.f = f;
    uint r = (c.u + 0x7FFFu + ((c.u >> 16) & 1u)) >> 16;
    return (unsigned short)r;
}
__device__ inline float bfhi(uint u) {  // high ushort -> float
    union { uint u; float f; } c; c.u = u & 0xFFFF0000u;
    return c.f;
}
__device__ inline float bflo(uint u) {  // low ushort -> float
    union { uint u; float f; } c; c.u = u << 16;
    return c.f;
}

// ---------------- init: deg=1 (self loop), colsum=0 ----------------
__global__ void k_init(int* deg, float* colsum, int n) {
    int i = blockIdx.x * blockDim.x + threadIdx.x;
    if (i < n) deg[i] = 1;
    if (i < FEAT) colsum[i] = 0.f;
}

// ---------------- histogram of dst (int32 edge list) ----------------
__global__ void k_hist(const int* __restrict__ dst, int* deg, int E) {
    int e = blockIdx.x * blockDim.x + threadIdx.x;
    if (e < E) atomicAdd(&deg[dst[e]], 1);
}

// ---------------- hierarchical scan, stage 1: per-block sums of (deg-1) ----------------
__global__ __launch_bounds__(256) void k_bsum(const int* __restrict__ deg,
                                              int* __restrict__ bsum, int n) {
    int i = blockIdx.x * 256 + threadIdx.x;
    int v = (i < n) ? (deg[i] - 1) : 0;
    #pragma unroll
    for (int d = 32; d; d >>= 1) v += __shfl_down(v, d, 64);
    __shared__ int ws[4];
    int lane = threadIdx.x & 63, wid = threadIdx.x >> 6;
    if (lane == 0) ws[wid] = v;
    __syncthreads();
    if (threadIdx.x == 0) bsum[blockIdx.x] = ws[0] + ws[1] + ws[2] + ws[3];
}

// ---------------- stage 2: exclusive scan of block sums (nb <= 256) ----------------
__global__ __launch_bounds__(256) void k_bscan(int* bsum, int nb) {
    __shared__ int lds[256];
    int t = threadIdx.x;
    int v = (t < nb) ? bsum[t] : 0;
    lds[t] = v;
    __syncthreads();
    #pragma unroll
    for (int d = 1; d < 256; d <<= 1) {
        int u = (t >= d) ? lds[t - d] : 0;
        __syncthreads();
        lds[t] += u;
        __syncthreads();
    }
    if (t < nb) bsum[t] = lds[t] - v;  // exclusive prefix
}

// ---------------- stage 3: block-local scan + offset -> off/cursor/dinv ----------------
__global__ __launch_bounds__(256) void k_write(const int* __restrict__ deg,
                                               const int* __restrict__ bsum,
                                               int* off, int* cursor, float* dinv,
                                               int n, int E) {
    __shared__ int lds[256];
    int t = threadIdx.x;
    int i = blockIdx.x * 256 + t;
    int v = (i < n) ? (deg[i] - 1) : 0;
    lds[t] = v;
    __syncthreads();
    #pragma unroll
    for (int d = 1; d < 256; d <<= 1) {
        int u = (t >= d) ? lds[t - d] : 0;
        __syncthreads();
        lds[t] += u;
        __syncthreads();
    }
    if (i < n) {
        int o = bsum[blockIdx.x] + (lds[t] - v);
        off[i] = o;
        cursor[i] = o;
        dinv[i] = rsqrtf((float)deg[i]);
    }
    if (i == n - 1) off[n] = E;  // every edge lands in [0,n): total incoming == E
}

// ---------------- fill CSR (by dst), store src ----------------
__global__ void k_fill(const int* __restrict__ src, const int* __restrict__ dst,
                       int* cursor, int* csr, int E) {
    int e = blockIdx.x * blockDim.x + threadIdx.x;
    if (e < E) {
        int d = dst[e];
        int pos = atomicAdd(&cursor[d], 1);
        csr[pos] = src[e];
    }
}

// ---------------- split dual GEMM ----------------
// which==0: hs = (x@W)*dinv[row] stored as BF16 (halves gather traffic in k_agg)
// which==1: xs = x@Ws + (b+bs) stored fp32
__global__ __launch_bounds__(256) void k_gemm(
    const float* __restrict__ x, const float* __restrict__ W,
    const float* __restrict__ Ws, const float* __restrict__ b,
    const float* __restrict__ bs, const float* __restrict__ dinv,
    unsigned short* __restrict__ hs, float* __restrict__ xs, int n) {
    __shared__ float x_lds[64 * FEAT];  // 32 KB
    int tid = threadIdx.x;
    int pair = blockIdx.x >> 1;
    int which = blockIdx.x & 1;
    int row0 = pair * 64;

    // stage x tile (coalesced float4)
    int c4 = (tid & 31) * 4;
    int rl = tid >> 5;  // 0..7
    #pragma unroll
    for (int p = 0; p < 8; ++p) {
        int r = rl + p * 8;
        float4 v = make_float4(0.f, 0.f, 0.f, 0.f);
        if (row0 + r < n) v = *(const float4*)&x[(size_t)(row0 + r) * FEAT + c4];
        *(float4*)&x_lds[r * FEAT + c4] = v;
    }
    __syncthreads();

    int ct = tid & 31;  // cols ct*4 .. ct*4+3
    int rt = tid >> 5;  // rows rt*8 .. rt*8+7
    float acc[8][4];
    #pragma unroll
    for (int i = 0; i < 8; ++i)
        #pragma unroll
        for (int j = 0; j < 4; ++j) acc[i][j] = 0.f;

    const float4* Mv = (const float4*)(which ? Ws : W) + ct;  // row k at Mv[k*32]
    for (int k = 0; k < FEAT; k += 4) {
        float4 b0 = Mv[(size_t)(k + 0) * 32];
        float4 b1 = Mv[(size_t)(k + 1) * 32];
        float4 b2 = Mv[(size_t)(k + 2) * 32];
        float4 b3 = Mv[(size_t)(k + 3) * 32];
        #pragma unroll
        for (int i = 0; i < 8; ++i) {
            float4 a = *(const float4*)&x_lds[(rt * 8 + i) * FEAT + k];
            acc[i][0] += a.x * b0.x; acc[i][1] += a.x * b0.y;
            acc[i][2] += a.x * b0.z; acc[i][3] += a.x * b0.w;
            acc[i][0] += a.y * b1.x; acc[i][1] += a.y * b1.y;
            acc[i][2] += a.y * b1.z; acc[i][3] += a.y * b1.w;
            acc[i][0] += a.z * b2.x; acc[i][1] += a.z * b2.y;
            acc[i][2] += a.z * b2.z; acc[i][3] += a.z * b2.w;
            acc[i][0] += a.w * b3.x; acc[i][1] += a.w * b3.y;
            acc[i][2] += a.w * b3.z; acc[i][3] += a.w * b3.w;
        }
    }

    if (which == 0) {
        #pragma unroll
        for (int i = 0; i < 8; ++i) {
            int r = row0 + rt * 8 + i;
            if (r < n) {
                float dv = dinv[r];
                // pack 4 bf16 into uint2, 8B coalesced store
                uint p0 = (uint)f2bf(acc[i][0] * dv) | ((uint)f2bf(acc[i][1] * dv) << 16);
                uint p1 = (uint)f2bf(acc[i][2] * dv) | ((uint)f2bf(acc[i][3] * dv) << 16);
                uint2 pk; pk.x = p0; pk.y = p1;
                *(uint2*)&hs[(size_t)r * FEAT + ct * 4] = pk;
            }
        }
    } else {
        float4 bb  = *(const float4*)&b[ct * 4];
        float4 bb2 = *(const float4*)&bs[ct * 4];
        float4 bias = make_float4(bb.x + bb2.x, bb.y + bb2.y, bb.z + bb2.z, bb.w + bb2.w);
        #pragma unroll
        for (int i = 0; i < 8; ++i) {
            int r = row0 + rt * 8 + i;
            if (r < n) {
                size_t o = (size_t)r * FEAT + ct * 4;
                *(float4*)&xs[o] = make_float4(acc[i][0] + bias.x, acc[i][1] + bias.y,
                                               acc[i][2] + bias.z, acc[i][3] + bias.w);
            }
        }
    }
}

// ---------------- aggregation + skip + bias + relu (in place in xs) ----------------
// one node per 32-lane half-wave; bf16 rows: uint2 (8B) per lane = 256B/row,
// 4-way unroll -> 8 rows in flight per wave; fp32 accumulate.
__global__ __launch_bounds__(256) void k_agg(
    const unsigned short* __restrict__ hs, float* __restrict__ xs,
    const float* __restrict__ dinv, const int* __restrict__ off,
    const int* __restrict__ csr, int n) {
    int node = (blockIdx.x * 256 + threadIdx.x) >> 5;
    int sub = threadIdx.x & 31;
    if (node >= n) return;
    size_t fo = (size_t)sub * 4;
    const uint2* hp = (const uint2*)&hs[(size_t)node * FEAT + fo];
    uint2 p = *hp;  // self loop contribution (pre-scaled)
    float4 a0 = make_float4(bflo(p.x), bfhi(p.x), bflo(p.y), bfhi(p.y));
    float4 a1 = make_float4(0.f, 0.f, 0.f, 0.f);
    float4 a2 = make_float4(0.f, 0.f, 0.f, 0.f);
    float4 a3 = make_float4(0.f, 0.f, 0.f, 0.f);
    int s = off[node], e = off[node + 1];
    int j = s;
    for (; j + 4 <= e; j += 4) {
        int u0 = csr[j], u1 = csr[j + 1], u2 = csr[j + 2], u3 = csr[j + 3];
        uint2 q0 = *(const uint2*)&hs[(size_t)u0 * FEAT + fo];
        uint2 q1 = *(const uint2*)&hs[(size_t)u1 * FEAT + fo];
        uint2 q2 = *(const uint2*)&hs[(size_t)u2 * FEAT + fo];
        uint2 q3 = *(const uint2*)&hs[(size_t)u3 * FEAT + fo];
        a0.x += bflo(q0.x); a0.y += bfhi(q0.x); a0.z += bflo(q0.y); a0.w += bfhi(q0.y);
        a1.x += bflo(q1.x); a1.y += bfhi(q1.x); a1.z += bflo(q1.y); a1.w += bfhi(q1.y);
        a2.x += bflo(q2.x); a2.y += bfhi(q2.x); a2.z += bflo(q2.y); a2.w += bfhi(q2.y);
        a3.x += bflo(q3.x); a3.y += bfhi(q3.x); a3.z += bflo(q3.y); a3.w += bfhi(q3.y);
    }
    for (; j < e; ++j) {
        int u = csr[j];
        uint2 q = *(const uint2*)&hs[(size_t)u * FEAT + fo];
        a0.x += bflo(q.x); a0.y += bfhi(q.x); a0.z += bflo(q.y); a0.w += bfhi(q.y);
    }
    float4 acc;
    acc.x = (a0.x + a1.x) + (a2.x + a3.x);
    acc.y = (a0.y + a1.y) + (a2.y + a3.y);
    acc.z = (a0.z + a1.z) + (a2.z + a3.z);
    acc.w = (a0.w + a1.w) + (a2.w + a3.w);
    float dv = dinv[node];
    size_t o = (size_t)node * FEAT + fo;
    float4 sk = *(const float4*)&xs[o];
    float4 out;
    out.x = fmaxf(fmaf(acc.x, dv, sk.x), 0.f);
    out.y = fmaxf(fmaf(acc.y, dv, sk.y), 0.f);
    out.z = fmaxf(fmaf(acc.z, dv, sk.z), 0.f);
    out.w = fmaxf(fmaf(acc.w, dv, sk.w), 0.f);
    *(float4*)&xs[o] = out;
}

// ---------------- column sum (block-reduced, atomics on 128 addrs) ----------------
__global__ __launch_bounds__(256) void k_colsum(const float* __restrict__ x2,
                                                float* colsum, int n) {
    __shared__ float lds[256];
    int tid = threadIdx.x;
    int f = tid & 127;
    int half = tid >> 7;
    float acc = 0.f;
    for (int r = blockIdx.x * 2 + half; r < n; r += gridDim.x * 2)
        acc += x2[(size_t)r * FEAT + f];
    lds[tid] = acc;
    __syncthreads();
    if (tid < 128) atomicAdd(&colsum[f], lds[f] + lds[f + 128]);
}

// ---------------- final: (colsum/n) @ Wc + bc ----------------
__global__ void k_final(const float* __restrict__ colsum, const float* __restrict__ Wc,
                        const float* __restrict__ bc, float* out, int n) {
    int c = threadIdx.x;
    if (c < N_CLS) {
        float acc = 0.f;
        for (int f = 0; f < FEAT; ++f) acc += colsum[f] * Wc[f * N_CLS + c];
        out[c] = acc / (float)n + bc[c];
    }
}

extern "C" void kernel_launch(void* const* d_in, const int* in_sizes, int n_in,
                              void* d_out, int out_size, void* d_ws, size_t ws_size,
                              hipStream_t stream) {
    const float* x   = (const float*)d_in[0];
    const int*   ei  = (const int*)d_in[1];   // harness passes integer inputs as int32
    const float* W1  = (const float*)d_in[2];
    const float* b1  = (const float*)d_in[3];
    const float* Ws1 = (const float*)d_in[4];
    const float* bs1 = (const float*)d_in[5];
    const float* W2  = (const float*)d_in[6];
    const float* b2  = (const float*)d_in[7];
    const float* Ws2 = (const float*)d_in[8];
    const float* bs2 = (const float*)d_in[9];
    const float* Wc  = (const float*)d_in[10];
    const float* bc  = (const float*)d_in[11];
    float* out = (float*)d_out;

    const int n = in_sizes[0] / FEAT;
    const int E = in_sizes[1] / 2;
    const int* src = ei;
    const int* dst = ei + E;

    const int nb = (n + 255) / 256;  // 196 blocks (<= 256 for k_bscan)

    // workspace carve-out
    char* w = (char*)d_ws;
    auto alloc = [&](size_t bytes) -> void* {
        void* p = (void*)w;
        w += (bytes + 255) & ~(size_t)255;
        return p;
    };
    int*   deg    = (int*)alloc((size_t)n * 4);
    int*   off    = (int*)alloc(((size_t)n + 1) * 4);
    int*   cursor = (int*)alloc((size_t)n * 4);
    int*   csr    = (int*)alloc((size_t)E * 4);
    float* dinv   = (float*)alloc((size_t)n * 4);
    float* colsum = (float*)alloc(FEAT * 4);
    int*   bsum   = (int*)alloc((size_t)nb * 4);
    unsigned short* A = (unsigned short*)alloc((size_t)n * FEAT * 2);  // hs bf16 (both layers)
    float* B = (float*)alloc((size_t)n * FEAT * 4);  // xs1 -> out1 (layer-2 input)
    float* C = (float*)alloc((size_t)n * FEAT * 4);  // xs2 -> out2

    // graph prep
    k_init<<<nb, 256, 0, stream>>>(deg, colsum, n);
    k_hist<<<(E + 255) / 256, 256, 0, stream>>>(dst, deg, E);
    k_bsum<<<nb, 256, 0, stream>>>(deg, bsum, n);
    k_bscan<<<1, 256, 0, stream>>>(bsum, nb);
    k_write<<<nb, 256, 0, stream>>>(deg, bsum, off, cursor, dinv, n, E);
    k_fill<<<(E + 255) / 256, 256, 0, stream>>>(src, dst, cursor, csr, E);

    int gemm_grid = 2 * ((n + 63) / 64);  // pairs x {W-half, Ws-half}
    int agg_grid  = (n + 7) / 8;          // one node per 32-lane half-wave

    // layer 1
    k_gemm<<<gemm_grid, 256, 0, stream>>>(x, W1, Ws1, b1, bs1, dinv, A, B, n);
    k_agg<<<agg_grid, 256, 0, stream>>>(A, B, dinv, off, csr, n);
    // layer 2 (separate output buffer C: split blocks must not write their input)
    k_gemm<<<gemm_grid, 256, 0, stream>>>(B, W2, Ws2, b2, bs2, dinv, A, C, n);
    k_agg<<<agg_grid, 256, 0, stream>>>(A, C, dinv, off, csr, n);

    // readout
    k_colsum<<<512, 256, 0, stream>>>(C, colsum, n);
    k_final<<<1, 64, 0, stream>>>(colsum, Wc, bc, out, n);
}

// Round 10
// 377.975 us; speedup vs baseline: 1.2783x; 1.0344x over previous
//
#include <hip/hip_runtime.h>

#define FEAT 128
#define N_CLS 10

typedef unsigned int uint;
typedef __attribute__((ext_vector_type(8))) short short8v;  // 8 bf16 (4 VGPRs)
typedef __attribute__((ext_vector_type(4))) float f32x4;

// ---- bf16 helpers (manual, RNE pack / exact unpack) ----
__device__ inline unsigned short f2bf(float f) {
    union { float f; uint u; } c; c.f = f;
    uint r = (c.u + 0x7FFFu + ((c.u >> 16) & 1u)) >> 16;
    return (unsigned short)r;
}
__device__ inline float bfhi(uint u) {
    union { uint u; float f; } c; c.u = u & 0xFFFF0000u;
    return c.f;
}
__device__ inline float bflo(uint u) {
    union { uint u; float f; } c; c.u = u << 16;
    return c.f;
}

// ---------------- init: deg=1 (self loop), colsum=0 ----------------
__global__ void k_init(int* deg, float* colsum, int n) {
    int i = blockIdx.x * blockDim.x + threadIdx.x;
    if (i < n) deg[i] = 1;
    if (i < FEAT) colsum[i] = 0.f;
}

// ---------------- histogram of dst (int32 edge list) ----------------
__global__ void k_hist(const int* __restrict__ dst, int* deg, int E) {
    int e = blockIdx.x * blockDim.x + threadIdx.x;
    if (e < E) atomicAdd(&deg[dst[e]], 1);
}

// ---------------- hierarchical scan, stage 1 ----------------
__global__ __launch_bounds__(256) void k_bsum(const int* __restrict__ deg,
                                              int* __restrict__ bsum, int n) {
    int i = blockIdx.x * 256 + threadIdx.x;
    int v = (i < n) ? (deg[i] - 1) : 0;
    #pragma unroll
    for (int d = 32; d; d >>= 1) v += __shfl_down(v, d, 64);
    __shared__ int ws[4];
    int lane = threadIdx.x & 63, wid = threadIdx.x >> 6;
    if (lane == 0) ws[wid] = v;
    __syncthreads();
    if (threadIdx.x == 0) bsum[blockIdx.x] = ws[0] + ws[1] + ws[2] + ws[3];
}

// ---------------- stage 2: exclusive scan of block sums ----------------
__global__ __launch_bounds__(256) void k_bscan(int* bsum, int nb) {
    __shared__ int lds[256];
    int t = threadIdx.x;
    int v = (t < nb) ? bsum[t] : 0;
    lds[t] = v;
    __syncthreads();
    #pragma unroll
    for (int d = 1; d < 256; d <<= 1) {
        int u = (t >= d) ? lds[t - d] : 0;
        __syncthreads();
        lds[t] += u;
        __syncthreads();
    }
    if (t < nb) bsum[t] = lds[t] - v;
}

// ---------------- stage 3: off/cursor/dinv ----------------
__global__ __launch_bounds__(256) void k_write(const int* __restrict__ deg,
                                               const int* __restrict__ bsum,
                                               int* off, int* cursor, float* dinv,
                                               int n, int E) {
    __shared__ int lds[256];
    int t = threadIdx.x;
    int i = blockIdx.x * 256 + t;
    int v = (i < n) ? (deg[i] - 1) : 0;
    lds[t] = v;
    __syncthreads();
    #pragma unroll
    for (int d = 1; d < 256; d <<= 1) {
        int u = (t >= d) ? lds[t - d] : 0;
        __syncthreads();
        lds[t] += u;
        __syncthreads();
    }
    if (i < n) {
        int o = bsum[blockIdx.x] + (lds[t] - v);
        off[i] = o;
        cursor[i] = o;
        dinv[i] = rsqrtf((float)deg[i]);
    }
    if (i == n - 1) off[n] = E;
}

// ---------------- fill CSR (by dst), store src ----------------
__global__ void k_fill(const int* __restrict__ src, const int* __restrict__ dst,
                       int* cursor, int* csr, int E) {
    int e = blockIdx.x * blockDim.x + threadIdx.x;
    if (e < E) {
        int d = dst[e];
        int pos = atomicAdd(&cursor[d], 1);
        csr[pos] = src[e];
    }
}

// ---------------- transpose W (fp32 row-major) -> Wt (bf16 [col][k]) ----------------
__global__ __launch_bounds__(256) void k_trans(const float* __restrict__ Wsrc,
                                               unsigned short* __restrict__ Wt) {
    int idx = blockIdx.x * 256 + threadIdx.x;  // 16384 threads
    int c = idx >> 7, k = idx & 127;
    Wt[c * FEAT + k] = f2bf(Wsrc[k * FEAT + c]);  // write coalesced along k
}

// ---------------- MFMA split dual GEMM (bf16 in, fp32 acc) ----------------
// pair = blockIdx.x>>1 covers 64 rows; which = blockIdx.x&1:
//   which==0: hs = (x@W)*dinv  (bf16 out)     which==1: xs = x@Ws + (b+bs) (fp32 out)
// 4 waves x 16 rows; 8 col-tiles x 4 k-steps of v_mfma_f32_16x16x32_bf16.
// A-frag: lane lr=lane&15 -> row, lg=lane>>4 -> k-octet, from bf16 LDS tile.
// B-frag: Wt[col][k] bf16 global (32KB, L2-resident). C/D: col=lane&15,
// row=(lane>>4)*4+reg (m89-verified).
__global__ __launch_bounds__(256) void k_gemm(
    const float* __restrict__ x, const unsigned short* __restrict__ Wt,
    const unsigned short* __restrict__ Wst, const float* __restrict__ b,
    const float* __restrict__ bs, const float* __restrict__ dinv,
    unsigned short* __restrict__ hs, float* __restrict__ xs, int n) {
    __shared__ unsigned short x_lds[64 * 136];  // +8 bf16 pad: 2-way bank alias (free)
    int tid = threadIdx.x;
    int pair = blockIdx.x >> 1;
    int which = blockIdx.x & 1;
    int row0 = pair * 64;

    // stage x tile -> bf16 LDS (coalesced float4 read, 8B LDS write)
    int c4 = (tid & 31) * 4;
    int rl = tid >> 5;  // 0..7
    #pragma unroll
    for (int p = 0; p < 8; ++p) {
        int r = rl + p * 8;
        float4 v = make_float4(0.f, 0.f, 0.f, 0.f);
        if (row0 + r < n) v = *(const float4*)&x[(size_t)(row0 + r) * FEAT + c4];
        uint2 pk;
        pk.x = (uint)f2bf(v.x) | ((uint)f2bf(v.y) << 16);
        pk.y = (uint)f2bf(v.z) | ((uint)f2bf(v.w) << 16);
        *(uint2*)&x_lds[r * 136 + c4] = pk;
    }
    __syncthreads();

    int wv = tid >> 6;        // wave 0..3 -> rows wv*16..+15
    int lane = tid & 63;
    int lr = lane & 15;       // A-row / B-col / D-col within tile
    int lg = lane >> 4;       // k-octet group

    // A fragments for all 4 k-steps (16 VGPRs)
    short8v a[4];
    #pragma unroll
    for (int ks = 0; ks < 4; ++ks)
        a[ks] = *(const short8v*)&x_lds[(wv * 16 + lr) * 136 + ks * 32 + lg * 8];

    const unsigned short* Wp = which ? Wst : Wt;
    f32x4 acc[8];
    #pragma unroll
    for (int ct = 0; ct < 8; ++ct) acc[ct] = (f32x4){0.f, 0.f, 0.f, 0.f};

    #pragma unroll
    for (int ct = 0; ct < 8; ++ct) {
        #pragma unroll
        for (int ks = 0; ks < 4; ++ks) {
            short8v bf = *(const short8v*)&Wp[(size_t)(ct * 16 + lr) * FEAT + ks * 32 + lg * 8];
            acc[ct] = __builtin_amdgcn_mfma_f32_16x16x32_bf16(a[ks], bf, acc[ct], 0, 0, 0);
        }
    }

    // epilogue: lane covers col=ct*16+lr, rows rbase..rbase+3
    int rbase = row0 + wv * 16 + lg * 4;
    if (which == 0) {
        float dv[4];
        #pragma unroll
        for (int j = 0; j < 4; ++j) dv[j] = (rbase + j < n) ? dinv[rbase + j] : 0.f;
        #pragma unroll
        for (int ct = 0; ct < 8; ++ct) {
            int col = ct * 16 + lr;
            #pragma unroll
            for (int j = 0; j < 4; ++j) {
                int r = rbase + j;
                if (r < n) hs[(size_t)r * FEAT + col] = f2bf(acc[ct][j] * dv[j]);
            }
        }
    } else {
        #pragma unroll
        for (int ct = 0; ct < 8; ++ct) {
            int col = ct * 16 + lr;
            float bias = b[col] + bs[col];
            #pragma unroll
            for (int j = 0; j < 4; ++j) {
                int r = rbase + j;
                if (r < n) xs[(size_t)r * FEAT + col] = acc[ct][j] + bias;
            }
        }
    }
}

// ---------------- aggregation + skip + bias + relu (in place in xs) ----------------
__global__ __launch_bounds__(256) void k_agg(
    const unsigned short* __restrict__ hs, float* __restrict__ xs,
    const float* __restrict__ dinv, const int* __restrict__ off,
    const int* __restrict__ csr, int n) {
    int node = (blockIdx.x * 256 + threadIdx.x) >> 5;
    int sub = threadIdx.x & 31;
    if (node >= n) return;
    size_t fo = (size_t)sub * 4;
    const uint2* hp = (const uint2*)&hs[(size_t)node * FEAT + fo];
    uint2 p = *hp;  // self loop contribution (pre-scaled)
    float4 a0 = make_float4(bflo(p.x), bfhi(p.x), bflo(p.y), bfhi(p.y));
    float4 a1 = make_float4(0.f, 0.f, 0.f, 0.f);
    float4 a2 = make_float4(0.f, 0.f, 0.f, 0.f);
    float4 a3 = make_float4(0.f, 0.f, 0.f, 0.f);
    int s = off[node], e = off[node + 1];
    int j = s;
    for (; j + 4 <= e; j += 4) {
        int u0 = csr[j], u1 = csr[j + 1], u2 = csr[j + 2], u3 = csr[j + 3];
        uint2 q0 = *(const uint2*)&hs[(size_t)u0 * FEAT + fo];
        uint2 q1 = *(const uint2*)&hs[(size_t)u1 * FEAT + fo];
        uint2 q2 = *(const uint2*)&hs[(size_t)u2 * FEAT + fo];
        uint2 q3 = *(const uint2*)&hs[(size_t)u3 * FEAT + fo];
        a0.x += bflo(q0.x); a0.y += bfhi(q0.x); a0.z += bflo(q0.y); a0.w += bfhi(q0.y);
        a1.x += bflo(q1.x); a1.y += bfhi(q1.x); a1.z += bflo(q1.y); a1.w += bfhi(q1.y);
        a2.x += bflo(q2.x); a2.y += bfhi(q2.x); a2.z += bflo(q2.y); a2.w += bfhi(q2.y);
        a3.x += bflo(q3.x); a3.y += bfhi(q3.x); a3.z += bflo(q3.y); a3.w += bfhi(q3.y);
    }
    for (; j < e; ++j) {
        int u = csr[j];
        uint2 q = *(const uint2*)&hs[(size_t)u * FEAT + fo];
        a0.x += bflo(q.x); a0.y += bfhi(q.x); a0.z += bflo(q.y); a0.w += bfhi(q.y);
    }
    float4 acc;
    acc.x = (a0.x + a1.x) + (a2.x + a3.x);
    acc.y = (a0.y + a1.y) + (a2.y + a3.y);
    acc.z = (a0.z + a1.z) + (a2.z + a3.z);
    acc.w = (a0.w + a1.w) + (a2.w + a3.w);
    float dv = dinv[node];
    size_t o = (size_t)node * FEAT + fo;
    float4 sk = *(const float4*)&xs[o];
    float4 out;
    out.x = fmaxf(fmaf(acc.x, dv, sk.x), 0.f);
    out.y = fmaxf(fmaf(acc.y, dv, sk.y), 0.f);
    out.z = fmaxf(fmaf(acc.z, dv, sk.z), 0.f);
    out.w = fmaxf(fmaf(acc.w, dv, sk.w), 0.f);
    *(float4*)&xs[o] = out;
}

// ---------------- column sum ----------------
__global__ __launch_bounds__(256) void k_colsum(const float* __restrict__ x2,
                                                float* colsum, int n) {
    __shared__ float lds[256];
    int tid = threadIdx.x;
    int f = tid & 127;
    int half = tid >> 7;
    float acc = 0.f;
    for (int r = blockIdx.x * 2 + half; r < n; r += gridDim.x * 2)
        acc += x2[(size_t)r * FEAT + f];
    lds[tid] = acc;
    __syncthreads();
    if (tid < 128) atomicAdd(&colsum[f], lds[f] + lds[f + 128]);
}

// ---------------- final: (colsum/n) @ Wc + bc ----------------
__global__ void k_final(const float* __restrict__ colsum, const float* __restrict__ Wc,
                        const float* __restrict__ bc, float* out, int n) {
    int c = threadIdx.x;
    if (c < N_CLS) {
        float acc = 0.f;
        for (int f = 0; f < FEAT; ++f) acc += colsum[f] * Wc[f * N_CLS + c];
        out[c] = acc / (float)n + bc[c];
    }
}

extern "C" void kernel_launch(void* const* d_in, const int* in_sizes, int n_in,
                              void* d_out, int out_size, void* d_ws, size_t ws_size,
                              hipStream_t stream) {
    const float* x   = (const float*)d_in[0];
    const int*   ei  = (const int*)d_in[1];
    const float* W1  = (const float*)d_in[2];
    const float* b1  = (const float*)d_in[3];
    const float* Ws1 = (const float*)d_in[4];
    const float* bs1 = (const float*)d_in[5];
    const float* W2  = (const float*)d_in[6];
    const float* b2  = (const float*)d_in[7];
    const float* Ws2 = (const float*)d_in[8];
    const float* bs2 = (const float*)d_in[9];
    const float* Wc  = (const float*)d_in[10];
    const float* bc  = (const float*)d_in[11];
    float* out = (float*)d_out;

    const int n = in_sizes[0] / FEAT;
    const int E = in_sizes[1] / 2;
    const int* src = ei;
    const int* dst = ei + E;

    const int nb = (n + 255) / 256;

    char* w = (char*)d_ws;
    auto alloc = [&](size_t bytes) -> void* {
        void* p = (void*)w;
        w += (bytes + 255) & ~(size_t)255;
        return p;
    };
    int*   deg    = (int*)alloc((size_t)n * 4);
    int*   off    = (int*)alloc(((size_t)n + 1) * 4);
    int*   cursor = (int*)alloc((size_t)n * 4);
    int*   csr    = (int*)alloc((size_t)E * 4);
    float* dinv   = (float*)alloc((size_t)n * 4);
    float* colsum = (float*)alloc(FEAT * 4);
    int*   bsum   = (int*)alloc((size_t)nb * 4);
    unsigned short* Wt1  = (unsigned short*)alloc(FEAT * FEAT * 2);
    unsigned short* Wst1 = (unsigned short*)alloc(FEAT * FEAT * 2);
    unsigned short* Wt2  = (unsigned short*)alloc(FEAT * FEAT * 2);
    unsigned short* Wst2 = (unsigned short*)alloc(FEAT * FEAT * 2);
    unsigned short* A = (unsigned short*)alloc((size_t)n * FEAT * 2);  // hs bf16
    float* B = (float*)alloc((size_t)n * FEAT * 4);  // xs1 -> out1
    float* C = (float*)alloc((size_t)n * FEAT * 4);  // xs2 -> out2

    // graph prep
    k_init<<<nb, 256, 0, stream>>>(deg, colsum, n);
    k_hist<<<(E + 255) / 256, 256, 0, stream>>>(dst, deg, E);
    k_bsum<<<nb, 256, 0, stream>>>(deg, bsum, n);
    k_bscan<<<1, 256, 0, stream>>>(bsum, nb);
    k_write<<<nb, 256, 0, stream>>>(deg, bsum, off, cursor, dinv, n, E);
    k_fill<<<(E + 255) / 256, 256, 0, stream>>>(src, dst, cursor, csr, E);

    // weight transposes (bf16, L2-resident)
    k_trans<<<64, 256, 0, stream>>>(W1, Wt1);
    k_trans<<<64, 256, 0, stream>>>(Ws1, Wst1);
    k_trans<<<64, 256, 0, stream>>>(W2, Wt2);
    k_trans<<<64, 256, 0, stream>>>(Ws2, Wst2);

    int gemm_grid = 2 * ((n + 63) / 64);
    int agg_grid  = (n + 7) / 8;

    // layer 1
    k_gemm<<<gemm_grid, 256, 0, stream>>>(x, Wt1, Wst1, b1, bs1, dinv, A, B, n);
    k_agg<<<agg_grid, 256, 0, stream>>>(A, B, dinv, off, csr, n);
    // layer 2
    k_gemm<<<gemm_grid, 256, 0, stream>>>(B, Wt2, Wst2, b2, bs2, dinv, A, C, n);
    k_agg<<<agg_grid, 256, 0, stream>>>(A, C, dinv, off, csr, n);

    // readout
    k_colsum<<<512, 256, 0, stream>>>(C, colsum, n);
    k_final<<<1, 64, 0, stream>>>(colsum, Wc, bc, out, n);
}

// Round 11
// 342.072 us; speedup vs baseline: 1.4124x; 1.1050x over previous
//
#include <hip/hip_runtime.h>

#define FEAT 128
#define N_CLS 10

typedef unsigned int uint;
typedef __attribute__((ext_vector_type(8))) short short8v;  // 8 bf16 (4 VGPRs)
typedef __attribute__((ext_vector_type(4))) float f32x4;

// ---- bf16 helpers (manual, RNE pack / exact unpack) ----
__device__ inline unsigned short f2bf(float f) {
    union { float f; uint u; } c; c.f = f;
    uint r = (c.u + 0x7FFFu + ((c.u >> 16) & 1u)) >> 16;
    return (unsigned short)r;
}
__device__ inline float bfhi(uint u) {
    union { uint u; float f; } c; c.u = u & 0xFFFF0000u;
    return c.f;
}
__device__ inline float bflo(uint u) {
    union { uint u; float f; } c; c.u = u << 16;
    return c.f;
}

// ---------------- init: deg=0 (in-edge count), colsum=0 ----------------
__global__ void k_init(int* deg, float* colsum, int n) {
    int i = blockIdx.x * blockDim.x + threadIdx.x;
    if (i < n) deg[i] = 0;
    if (i < FEAT) colsum[i] = 0.f;
}

// ---------------- histogram of dst + per-edge rank (atomic return value) ----------------
__global__ void k_hist(const int* __restrict__ dst, int* deg,
                       unsigned short* __restrict__ rank, int E) {
    int e = blockIdx.x * blockDim.x + threadIdx.x;
    if (e < E) {
        int r = atomicAdd(&deg[dst[e]], 1);
        rank[e] = (unsigned short)r;  // in-degree << 65536 for uniform-random edges
    }
}

// ---------------- hierarchical scan, stage 1: per-block sums of deg ----------------
__global__ __launch_bounds__(256) void k_bsum(const int* __restrict__ deg,
                                              int* __restrict__ bsum, int n) {
    int i = blockIdx.x * 256 + threadIdx.x;
    int v = (i < n) ? deg[i] : 0;
    #pragma unroll
    for (int d = 32; d; d >>= 1) v += __shfl_down(v, d, 64);
    __shared__ int ws[4];
    int lane = threadIdx.x & 63, wid = threadIdx.x >> 6;
    if (lane == 0) ws[wid] = v;
    __syncthreads();
    if (threadIdx.x == 0) bsum[blockIdx.x] = ws[0] + ws[1] + ws[2] + ws[3];
}

// ---------------- stage 2: exclusive scan of block sums ----------------
__global__ __launch_bounds__(256) void k_bscan(int* bsum, int nb) {
    __shared__ int lds[256];
    int t = threadIdx.x;
    int v = (t < nb) ? bsum[t] : 0;
    lds[t] = v;
    __syncthreads();
    #pragma unroll
    for (int d = 1; d < 256; d <<= 1) {
        int u = (t >= d) ? lds[t - d] : 0;
        __syncthreads();
        lds[t] += u;
        __syncthreads();
    }
    if (t < nb) bsum[t] = lds[t] - v;
}

// ---------------- stage 3: off/dinv (deg = in-degree; +1 for self loop) ----------------
__global__ __launch_bounds__(256) void k_write(const int* __restrict__ deg,
                                               const int* __restrict__ bsum,
                                               int* off, float* dinv,
                                               int n, int E) {
    __shared__ int lds[256];
    int t = threadIdx.x;
    int i = blockIdx.x * 256 + t;
    int v = (i < n) ? deg[i] : 0;
    lds[t] = v;
    __syncthreads();
    #pragma unroll
    for (int d = 1; d < 256; d <<= 1) {
        int u = (t >= d) ? lds[t - d] : 0;
        __syncthreads();
        lds[t] += u;
        __syncthreads();
    }
    if (i < n) {
        off[i] = bsum[blockIdx.x] + (lds[t] - v);
        dinv[i] = rsqrtf((float)(deg[i] + 1));
    }
    if (i == n - 1) off[n] = E;
}

// ---------------- fill CSR (atomic-free via precomputed rank) ----------------
__global__ void k_fill(const int* __restrict__ src, const int* __restrict__ dst,
                       const unsigned short* __restrict__ rank,
                       const int* __restrict__ off, int* __restrict__ csr, int E) {
    int e = blockIdx.x * blockDim.x + threadIdx.x;
    if (e < E) {
        int d = dst[e];
        csr[off[d] + (int)rank[e]] = src[e];
    }
}

// ---------------- transpose W (fp32 row-major) -> Wt (bf16 [col][k]) ----------------
__global__ __launch_bounds__(256) void k_trans(const float* __restrict__ Wsrc,
                                               unsigned short* __restrict__ Wt) {
    int idx = blockIdx.x * 256 + threadIdx.x;  // 16384 threads
    int c = idx >> 7, k = idx & 127;
    Wt[c * FEAT + k] = f2bf(Wsrc[k * FEAT + c]);
}

// ---------------- MFMA split dual GEMM (bf16 in, fp32 acc) ----------------
// pair = blockIdx.x>>1 covers 64 rows; which = blockIdx.x&1:
//   which==0: hs = (x@W)*dinv (bf16)      which==1: xs = x@Ws + (b+bs) (fp32)
// SWAPPED operands: mfma(w_frag, x_frag) -> D[m=weight-col][n=node].
// Lane l: node = l&15, cols = ct*16 + (l>>4)*4 + {0..3} -> vectorized
// uint2 (hs) / float4 (xs) epilogue stores, single dinv load per lane.
__global__ __launch_bounds__(256) void k_gemm(
    const float* __restrict__ x, const unsigned short* __restrict__ Wt,
    const unsigned short* __restrict__ Wst, const float* __restrict__ b,
    const float* __restrict__ bs, const float* __restrict__ dinv,
    unsigned short* __restrict__ hs, float* __restrict__ xs, int n) {
    __shared__ unsigned short x_lds[64 * 136];  // +8 bf16 pad
    int tid = threadIdx.x;
    int pair = blockIdx.x >> 1;
    int which = blockIdx.x & 1;
    int row0 = pair * 64;

    // stage x tile -> bf16 LDS (coalesced float4 read, 8B LDS write)
    int c4 = (tid & 31) * 4;
    int rl = tid >> 5;  // 0..7
    #pragma unroll
    for (int p = 0; p < 8; ++p) {
        int r = rl + p * 8;
        float4 v = make_float4(0.f, 0.f, 0.f, 0.f);
        if (row0 + r < n) v = *(const float4*)&x[(size_t)(row0 + r) * FEAT + c4];
        uint2 pk;
        pk.x = (uint)f2bf(v.x) | ((uint)f2bf(v.y) << 16);
        pk.y = (uint)f2bf(v.z) | ((uint)f2bf(v.w) << 16);
        *(uint2*)&x_lds[r * 136 + c4] = pk;
    }
    __syncthreads();

    int wv = tid >> 6;        // wave 0..3 -> nodes wv*16..+15
    int lane = tid & 63;
    int lr = lane & 15;       // node index within wave's 16 / weight-col within A-tile
    int lg = lane >> 4;       // k-octet group

    // x fragments (B operand): B[k][n=lr] = x[node lr][k]
    short8v a[4];
    #pragma unroll
    for (int ks = 0; ks < 4; ++ks)
        a[ks] = *(const short8v*)&x_lds[(wv * 16 + lr) * 136 + ks * 32 + lg * 8];

    const unsigned short* Wp = which ? Wst : Wt;
    f32x4 acc[8];
    #pragma unroll
    for (int ct = 0; ct < 8; ++ct) acc[ct] = (f32x4){0.f, 0.f, 0.f, 0.f};

    #pragma unroll
    for (int ct = 0; ct < 8; ++ct) {
        #pragma unroll
        for (int ks = 0; ks < 4; ++ks) {
            // W fragment (A operand): A[m=lr][k] = Wt[ct*16+lr][k]
            short8v bf = *(const short8v*)&Wp[(size_t)(ct * 16 + lr) * FEAT + ks * 32 + lg * 8];
            acc[ct] = __builtin_amdgcn_mfma_f32_16x16x32_bf16(bf, a[ks], acc[ct], 0, 0, 0);
        }
    }

    // epilogue: lane owns node, 4 consecutive cols per ct
    int node = row0 + wv * 16 + lr;
    int cb4 = lg * 4;
    if (node < n) {
        if (which == 0) {
            float dv = dinv[node];
            #pragma unroll
            for (int ct = 0; ct < 8; ++ct) {
                int col = ct * 16 + cb4;
                uint2 pk;
                pk.x = (uint)f2bf(acc[ct][0] * dv) | ((uint)f2bf(acc[ct][1] * dv) << 16);
                pk.y = (uint)f2bf(acc[ct][2] * dv) | ((uint)f2bf(acc[ct][3] * dv) << 16);
                *(uint2*)&hs[(size_t)node * FEAT + col] = pk;
            }
        } else {
            #pragma unroll
            for (int ct = 0; ct < 8; ++ct) {
                int col = ct * 16 + cb4;
                float4 bb  = *(const float4*)&b[col];
                float4 bb2 = *(const float4*)&bs[col];
                float4 o = make_float4(acc[ct][0] + bb.x + bb2.x,
                                       acc[ct][1] + bb.y + bb2.y,
                                       acc[ct][2] + bb.z + bb2.z,
                                       acc[ct][3] + bb.w + bb2.w);
                *(float4*)&xs[(size_t)node * FEAT + col] = o;
            }
        }
    }
}

// ---------------- aggregation + skip + bias + relu (in place in xs) ----------------
__global__ __launch_bounds__(256) void k_agg(
    const unsigned short* __restrict__ hs, float* __restrict__ xs,
    const float* __restrict__ dinv, const int* __restrict__ off,
    const int* __restrict__ csr, int n) {
    int node = (blockIdx.x * 256 + threadIdx.x) >> 5;
    int sub = threadIdx.x & 31;
    if (node >= n) return;
    size_t fo = (size_t)sub * 4;
    const uint2* hp = (const uint2*)&hs[(size_t)node * FEAT + fo];
    uint2 p = *hp;  // self loop contribution (pre-scaled)
    float4 a0 = make_float4(bflo(p.x), bfhi(p.x), bflo(p.y), bfhi(p.y));
    float4 a1 = make_float4(0.f, 0.f, 0.f, 0.f);
    float4 a2 = make_float4(0.f, 0.f, 0.f, 0.f);
    float4 a3 = make_float4(0.f, 0.f, 0.f, 0.f);
    int s = off[node], e = off[node + 1];
    int j = s;
    for (; j + 4 <= e; j += 4) {
        int u0 = csr[j], u1 = csr[j + 1], u2 = csr[j + 2], u3 = csr[j + 3];
        uint2 q0 = *(const uint2*)&hs[(size_t)u0 * FEAT + fo];
        uint2 q1 = *(const uint2*)&hs[(size_t)u1 * FEAT + fo];
        uint2 q2 = *(const uint2*)&hs[(size_t)u2 * FEAT + fo];
        uint2 q3 = *(const uint2*)&hs[(size_t)u3 * FEAT + fo];
        a0.x += bflo(q0.x); a0.y += bfhi(q0.x); a0.z += bflo(q0.y); a0.w += bfhi(q0.y);
        a1.x += bflo(q1.x); a1.y += bfhi(q1.x); a1.z += bflo(q1.y); a1.w += bfhi(q1.y);
        a2.x += bflo(q2.x); a2.y += bfhi(q2.x); a2.z += bflo(q2.y); a2.w += bfhi(q2.y);
        a3.x += bflo(q3.x); a3.y += bfhi(q3.x); a3.z += bflo(q3.y); a3.w += bfhi(q3.y);
    }
    for (; j < e; ++j) {
        int u = csr[j];
        uint2 q = *(const uint2*)&hs[(size_t)u * FEAT + fo];
        a0.x += bflo(q.x); a0.y += bfhi(q.x); a0.z += bflo(q.y); a0.w += bfhi(q.y);
    }
    float4 acc;
    acc.x = (a0.x + a1.x) + (a2.x + a3.x);
    acc.y = (a0.y + a1.y) + (a2.y + a3.y);
    acc.z = (a0.z + a1.z) + (a2.z + a3.z);
    acc.w = (a0.w + a1.w) + (a2.w + a3.w);
    float dv = dinv[node];
    size_t o = (size_t)node * FEAT + fo;
    float4 sk = *(const float4*)&xs[o];
    float4 out;
    out.x = fmaxf(fmaf(acc.x, dv, sk.x), 0.f);
    out.y = fmaxf(fmaf(acc.y, dv, sk.y), 0.f);
    out.z = fmaxf(fmaf(acc.z, dv, sk.z), 0.f);
    out.w = fmaxf(fmaf(acc.w, dv, sk.w), 0.f);
    *(float4*)&xs[o] = out;
}

// ---------------- column sum ----------------
__global__ __launch_bounds__(256) void k_colsum(const float* __restrict__ x2,
                                                float* colsum, int n) {
    __shared__ float lds[256];
    int tid = threadIdx.x;
    int f = tid & 127;
    int half = tid >> 7;
    float acc = 0.f;
    for (int r = blockIdx.x * 2 + half; r < n; r += gridDim.x * 2)
        acc += x2[(size_t)r * FEAT + f];
    lds[tid] = acc;
    __syncthreads();
    if (tid < 128) atomicAdd(&colsum[f], lds[f] + lds[f + 128]);
}

// ---------------- final: (colsum/n) @ Wc + bc ----------------
__global__ void k_final(const float* __restrict__ colsum, const float* __restrict__ Wc,
                        const float* __restrict__ bc, float* out, int n) {
    int c = threadIdx.x;
    if (c < N_CLS) {
        float acc = 0.f;
        for (int f = 0; f < FEAT; ++f) acc += colsum[f] * Wc[f * N_CLS + c];
        out[c] = acc / (float)n + bc[c];
    }
}

extern "C" void kernel_launch(void* const* d_in, const int* in_sizes, int n_in,
                              void* d_out, int out_size, void* d_ws, size_t ws_size,
                              hipStream_t stream) {
    const float* x   = (const float*)d_in[0];
    const int*   ei  = (const int*)d_in[1];
    const float* W1  = (const float*)d_in[2];
    const float* b1  = (const float*)d_in[3];
    const float* Ws1 = (const float*)d_in[4];
    const float* bs1 = (const float*)d_in[5];
    const float* W2  = (const float*)d_in[6];
    const float* b2  = (const float*)d_in[7];
    const float* Ws2 = (const float*)d_in[8];
    const float* bs2 = (const float*)d_in[9];
    const float* Wc  = (const float*)d_in[10];
    const float* bc  = (const float*)d_in[11];
    float* out = (float*)d_out;

    const int n = in_sizes[0] / FEAT;
    const int E = in_sizes[1] / 2;
    const int* src = ei;
    const int* dst = ei + E;

    const int nb = (n + 255) / 256;

    char* w = (char*)d_ws;
    auto alloc = [&](size_t bytes) -> void* {
        void* p = (void*)w;
        w += (bytes + 255) & ~(size_t)255;
        return p;
    };
    int*   deg    = (int*)alloc((size_t)n * 4);
    int*   off    = (int*)alloc(((size_t)n + 1) * 4);
    int*   csr    = (int*)alloc((size_t)E * 4);
    unsigned short* rank = (unsigned short*)alloc((size_t)E * 2);
    float* dinv   = (float*)alloc((size_t)n * 4);
    float* colsum = (float*)alloc(FEAT * 4);
    int*   bsum   = (int*)alloc((size_t)nb * 4);
    unsigned short* Wt1  = (unsigned short*)alloc(FEAT * FEAT * 2);
    unsigned short* Wst1 = (unsigned short*)alloc(FEAT * FEAT * 2);
    unsigned short* Wt2  = (unsigned short*)alloc(FEAT * FEAT * 2);
    unsigned short* Wst2 = (unsigned short*)alloc(FEAT * FEAT * 2);
    unsigned short* A = (unsigned short*)alloc((size_t)n * FEAT * 2);  // hs bf16
    float* B = (float*)alloc((size_t)n * FEAT * 4);  // xs1 -> out1
    float* C = (float*)alloc((size_t)n * FEAT * 4);  // xs2 -> out2

    // graph prep
    k_init<<<nb, 256, 0, stream>>>(deg, colsum, n);
    k_hist<<<(E + 255) / 256, 256, 0, stream>>>(dst, deg, rank, E);
    k_bsum<<<nb, 256, 0, stream>>>(deg, bsum, n);
    k_bscan<<<1, 256, 0, stream>>>(bsum, nb);
    k_write<<<nb, 256, 0, stream>>>(deg, bsum, off, dinv, n, E);
    k_fill<<<(E + 255) / 256, 256, 0, stream>>>(src, dst, rank, off, csr, E);

    // weight transposes (bf16, L2-resident)
    k_trans<<<64, 256, 0, stream>>>(W1, Wt1);
    k_trans<<<64, 256, 0, stream>>>(Ws1, Wst1);
    k_trans<<<64, 256, 0, stream>>>(W2, Wt2);
    k_trans<<<64, 256, 0, stream>>>(Ws2, Wst2);

    int gemm_grid = 2 * ((n + 63) / 64);
    int agg_grid  = (n + 7) / 8;

    // layer 1
    k_gemm<<<gemm_grid, 256, 0, stream>>>(x, Wt1, Wst1, b1, bs1, dinv, A, B, n);
    k_agg<<<agg_grid, 256, 0, stream>>>(A, B, dinv, off, csr, n);
    // layer 2
    k_gemm<<<gemm_grid, 256, 0, stream>>>(B, Wt2, Wst2, b2, bs2, dinv, A, C, n);
    k_agg<<<agg_grid, 256, 0, stream>>>(A, C, dinv, off, csr, n);

    // readout
    k_colsum<<<512, 256, 0, stream>>>(C, colsum, n);
    k_final<<<1, 64, 0, stream>>>(colsum, Wc, bc, out, n);
}

// Round 12
// 296.713 us; speedup vs baseline: 1.6283x; 1.1529x over previous
//
#include <hip/hip_runtime.h>

#define FEAT 128
#define N_CLS 10

typedef unsigned int uint;
typedef __attribute__((ext_vector_type(8))) short short8v;  // 8 bf16 (4 VGPRs)
typedef __attribute__((ext_vector_type(4))) float f32x4;

// ---- bf16 helpers (manual, RNE pack / exact unpack) ----
__device__ inline unsigned short f2bf(float f) {
    union { float f; uint u; } c; c.f = f;
    uint r = (c.u + 0x7FFFu + ((c.u >> 16) & 1u)) >> 16;
    return (unsigned short)r;
}
__device__ inline float bfhi(uint u) {
    union { uint u; float f; } c; c.u = u & 0xFFFF0000u;
    return c.f;
}
__device__ inline float bflo(uint u) {
    union { uint u; float f; } c; c.u = u << 16;
    return c.f;
}

// ---------------- init: deg=0 (in-edge count), colsum=0 ----------------
__global__ void k_init(int* deg, float* colsum, int n) {
    int i = blockIdx.x * blockDim.x + threadIdx.x;
    if (i < n) deg[i] = 0;
    if (i < FEAT) colsum[i] = 0.f;
}

// ---------------- histogram of dst + per-edge rank (atomic return value) ----------------
__global__ void k_hist(const int* __restrict__ dst, int* deg,
                       unsigned short* __restrict__ rank, int E) {
    int e = blockIdx.x * blockDim.x + threadIdx.x;
    if (e < E) {
        int r = atomicAdd(&deg[dst[e]], 1);
        rank[e] = (unsigned short)r;
    }
}

// ---------------- hierarchical scan, stage 1: per-block sums of deg ----------------
__global__ __launch_bounds__(256) void k_bsum(const int* __restrict__ deg,
                                              int* __restrict__ bsum, int n) {
    int i = blockIdx.x * 256 + threadIdx.x;
    int v = (i < n) ? deg[i] : 0;
    #pragma unroll
    for (int d = 32; d; d >>= 1) v += __shfl_down(v, d, 64);
    __shared__ int ws[4];
    int lane = threadIdx.x & 63, wid = threadIdx.x >> 6;
    if (lane == 0) ws[wid] = v;
    __syncthreads();
    if (threadIdx.x == 0) bsum[blockIdx.x] = ws[0] + ws[1] + ws[2] + ws[3];
}

// ---------------- stage 2: exclusive scan of block sums ----------------
__global__ __launch_bounds__(256) void k_bscan(int* bsum, int nb) {
    __shared__ int lds[256];
    int t = threadIdx.x;
    int v = (t < nb) ? bsum[t] : 0;
    lds[t] = v;
    __syncthreads();
    #pragma unroll
    for (int d = 1; d < 256; d <<= 1) {
        int u = (t >= d) ? lds[t - d] : 0;
        __syncthreads();
        lds[t] += u;
        __syncthreads();
    }
    if (t < nb) bsum[t] = lds[t] - v;
}

// ---------------- stage 3: off/dinv (deg = in-degree; +1 for self loop) ----------------
__global__ __launch_bounds__(256) void k_write(const int* __restrict__ deg,
                                               const int* __restrict__ bsum,
                                               int* off, float* dinv,
                                               int n, int E) {
    __shared__ int lds[256];
    int t = threadIdx.x;
    int i = blockIdx.x * 256 + t;
    int v = (i < n) ? deg[i] : 0;
    lds[t] = v;
    __syncthreads();
    #pragma unroll
    for (int d = 1; d < 256; d <<= 1) {
        int u = (t >= d) ? lds[t - d] : 0;
        __syncthreads();
        lds[t] += u;
        __syncthreads();
    }
    if (i < n) {
        off[i] = bsum[blockIdx.x] + (lds[t] - v);
        dinv[i] = rsqrtf((float)(deg[i] + 1));
    }
    if (i == n - 1) off[n] = E;
}

// ---------------- fill CSR (atomic-free via precomputed rank) ----------------
__global__ void k_fill(const int* __restrict__ src, const int* __restrict__ dst,
                       const unsigned short* __restrict__ rank,
                       const int* __restrict__ off, int* __restrict__ csr, int E) {
    int e = blockIdx.x * blockDim.x + threadIdx.x;
    if (e < E) {
        int d = dst[e];
        csr[off[d] + (int)rank[e]] = src[e];
    }
}

// ---------------- transpose W (fp32 row-major) -> Wt (bf16 [col][k]) ----------------
__global__ __launch_bounds__(256) void k_trans(const float* __restrict__ Wsrc,
                                               unsigned short* __restrict__ Wt) {
    int idx = blockIdx.x * 256 + threadIdx.x;  // 16384 threads
    int c = idx >> 7, k = idx & 127;
    Wt[c * FEAT + k] = f2bf(Wsrc[k * FEAT + c]);
}

// ---------------- MFMA split dual GEMM v3 (col-sliced waves, hoisted W) ----------------
// pair = blockIdx.x>>1 covers 64 rows; which = blockIdx.x&1:
//   which==0: hs = (x@W)*dinv (bf16)      which==1: xs = x@Ws + (b+bs) (fp32)
// Wave wv owns cols wv*32..+31 (2 ct-tiles) for ALL 64 nodes:
//   W fragments = 8 loads (32 VGPR), hoisted ONCE, reused by 4 node-groups.
// Inner loop per node-group: 4x ds_read_b128 + 8 MFMA (2 indep chains) + stores.
// D layout (swapped operands): node = lane&15, cols = ct*16+(lane>>4)*4+{0..3}.
__global__ __launch_bounds__(256) void k_gemm(
    const float* __restrict__ x, const unsigned short* __restrict__ Wt,
    const unsigned short* __restrict__ Wst, const float* __restrict__ b,
    const float* __restrict__ bs, const float* __restrict__ dinv,
    unsigned short* __restrict__ hs, float* __restrict__ xs, int n) {
    __shared__ unsigned short x_lds[64 * 136];  // +8 bf16 pad
    int tid = threadIdx.x;
    int pair = blockIdx.x >> 1;
    int which = blockIdx.x & 1;
    int row0 = pair * 64;

    // stage x tile -> bf16 LDS (coalesced float4 read, 8B LDS write)
    int c4 = (tid & 31) * 4;
    int rl = tid >> 5;  // 0..7
    #pragma unroll
    for (int p = 0; p < 8; ++p) {
        int r = rl + p * 8;
        float4 v = make_float4(0.f, 0.f, 0.f, 0.f);
        if (row0 + r < n) v = *(const float4*)&x[(size_t)(row0 + r) * FEAT + c4];
        uint2 pk;
        pk.x = (uint)f2bf(v.x) | ((uint)f2bf(v.y) << 16);
        pk.y = (uint)f2bf(v.z) | ((uint)f2bf(v.w) << 16);
        *(uint2*)&x_lds[r * 136 + c4] = pk;
    }

    int wv = tid >> 6;        // wave 0..3 -> col-tiles {2wv, 2wv+1}
    int lane = tid & 63;
    int lr = lane & 15;       // node-in-group / W-row-in-tile
    int lg = lane >> 4;       // k-octet group / col-quad selector
    int ctb = wv * 2;

    // hoist W fragments for this wave's 2 col-tiles (8 loads, 32 VGPR, reused 4x)
    const unsigned short* Wp = which ? Wst : Wt;
    short8v wf[2][4];
    #pragma unroll
    for (int c = 0; c < 2; ++c)
        #pragma unroll
        for (int ks = 0; ks < 4; ++ks)
            wf[c][ks] = *(const short8v*)&Wp[(size_t)((ctb + c) * 16 + lr) * FEAT + ks * 32 + lg * 8];

    // biases per col-quad (which==1 only; cols don't depend on node-group)
    float4 bias[2];
    #pragma unroll
    for (int c = 0; c < 2; ++c) {
        int col = (ctb + c) * 16 + lg * 4;
        float4 bb  = *(const float4*)&b[col];
        float4 bb2 = *(const float4*)&bs[col];
        bias[c] = make_float4(bb.x + bb2.x, bb.y + bb2.y, bb.z + bb2.z, bb.w + bb2.w);
    }

    __syncthreads();

    #pragma unroll
    for (int ng = 0; ng < 4; ++ng) {
        // x fragments (B operand) for this node-group from LDS
        short8v a[4];
        #pragma unroll
        for (int ks = 0; ks < 4; ++ks)
            a[ks] = *(const short8v*)&x_lds[(ng * 16 + lr) * 136 + ks * 32 + lg * 8];

        f32x4 acc[2];
        acc[0] = (f32x4){0.f, 0.f, 0.f, 0.f};
        acc[1] = (f32x4){0.f, 0.f, 0.f, 0.f};
        #pragma unroll
        for (int ks = 0; ks < 4; ++ks) {
            acc[0] = __builtin_amdgcn_mfma_f32_16x16x32_bf16(wf[0][ks], a[ks], acc[0], 0, 0, 0);
            acc[1] = __builtin_amdgcn_mfma_f32_16x16x32_bf16(wf[1][ks], a[ks], acc[1], 0, 0, 0);
        }

        int node = row0 + ng * 16 + lr;
        if (node < n) {
            if (which == 0) {
                float dv = dinv[node];
                #pragma unroll
                for (int c = 0; c < 2; ++c) {
                    int col = (ctb + c) * 16 + lg * 4;
                    uint2 pk;
                    pk.x = (uint)f2bf(acc[c][0] * dv) | ((uint)f2bf(acc[c][1] * dv) << 16);
                    pk.y = (uint)f2bf(acc[c][2] * dv) | ((uint)f2bf(acc[c][3] * dv) << 16);
                    *(uint2*)&hs[(size_t)node * FEAT + col] = pk;
                }
            } else {
                #pragma unroll
                for (int c = 0; c < 2; ++c) {
                    int col = (ctb + c) * 16 + lg * 4;
                    float4 o = make_float4(acc[c][0] + bias[c].x, acc[c][1] + bias[c].y,
                                           acc[c][2] + bias[c].z, acc[c][3] + bias[c].w);
                    *(float4*)&xs[(size_t)node * FEAT + col] = o;
                }
            }
        }
    }
}

// ---------------- aggregation + skip + bias + relu (in place in xs) ----------------
__global__ __launch_bounds__(256) void k_agg(
    const unsigned short* __restrict__ hs, float* __restrict__ xs,
    const float* __restrict__ dinv, const int* __restrict__ off,
    const int* __restrict__ csr, int n) {
    int node = (blockIdx.x * 256 + threadIdx.x) >> 5;
    int sub = threadIdx.x & 31;
    if (node >= n) return;
    size_t fo = (size_t)sub * 4;
    const uint2* hp = (const uint2*)&hs[(size_t)node * FEAT + fo];
    uint2 p = *hp;  // self loop contribution (pre-scaled)
    float4 a0 = make_float4(bflo(p.x), bfhi(p.x), bflo(p.y), bfhi(p.y));
    float4 a1 = make_float4(0.f, 0.f, 0.f, 0.f);
    float4 a2 = make_float4(0.f, 0.f, 0.f, 0.f);
    float4 a3 = make_float4(0.f, 0.f, 0.f, 0.f);
    int s = off[node], e = off[node + 1];
    int j = s;
    for (; j + 4 <= e; j += 4) {
        int u0 = csr[j], u1 = csr[j + 1], u2 = csr[j + 2], u3 = csr[j + 3];
        uint2 q0 = *(const uint2*)&hs[(size_t)u0 * FEAT + fo];
        uint2 q1 = *(const uint2*)&hs[(size_t)u1 * FEAT + fo];
        uint2 q2 = *(const uint2*)&hs[(size_t)u2 * FEAT + fo];
        uint2 q3 = *(const uint2*)&hs[(size_t)u3 * FEAT + fo];
        a0.x += bflo(q0.x); a0.y += bfhi(q0.x); a0.z += bflo(q0.y); a0.w += bfhi(q0.y);
        a1.x += bflo(q1.x); a1.y += bfhi(q1.x); a1.z += bflo(q1.y); a1.w += bfhi(q1.y);
        a2.x += bflo(q2.x); a2.y += bfhi(q2.x); a2.z += bflo(q2.y); a2.w += bfhi(q2.y);
        a3.x += bflo(q3.x); a3.y += bfhi(q3.x); a3.z += bflo(q3.y); a3.w += bfhi(q3.y);
    }
    for (; j < e; ++j) {
        int u = csr[j];
        uint2 q = *(const uint2*)&hs[(size_t)u * FEAT + fo];
        a0.x += bflo(q.x); a0.y += bfhi(q.x); a0.z += bflo(q.y); a0.w += bfhi(q.y);
    }
    float4 acc;
    acc.x = (a0.x + a1.x) + (a2.x + a3.x);
    acc.y = (a0.y + a1.y) + (a2.y + a3.y);
    acc.z = (a0.z + a1.z) + (a2.z + a3.z);
    acc.w = (a0.w + a1.w) + (a2.w + a3.w);
    float dv = dinv[node];
    size_t o = (size_t)node * FEAT + fo;
    float4 sk = *(const float4*)&xs[o];
    float4 out;
    out.x = fmaxf(fmaf(acc.x, dv, sk.x), 0.f);
    out.y = fmaxf(fmaf(acc.y, dv, sk.y), 0.f);
    out.z = fmaxf(fmaf(acc.z, dv, sk.z), 0.f);
    out.w = fmaxf(fmaf(acc.w, dv, sk.w), 0.f);
    *(float4*)&xs[o] = out;
}

// ---------------- column sum ----------------
__global__ __launch_bounds__(256) void k_colsum(const float* __restrict__ x2,
                                                float* colsum, int n) {
    __shared__ float lds[256];
    int tid = threadIdx.x;
    int f = tid & 127;
    int half = tid >> 7;
    float acc = 0.f;
    for (int r = blockIdx.x * 2 + half; r < n; r += gridDim.x * 2)
        acc += x2[(size_t)r * FEAT + f];
    lds[tid] = acc;
    __syncthreads();
    if (tid < 128) atomicAdd(&colsum[f], lds[f] + lds[f + 128]);
}

// ---------------- final: (colsum/n) @ Wc + bc ----------------
__global__ void k_final(const float* __restrict__ colsum, const float* __restrict__ Wc,
                        const float* __restrict__ bc, float* out, int n) {
    int c = threadIdx.x;
    if (c < N_CLS) {
        float acc = 0.f;
        for (int f = 0; f < FEAT; ++f) acc += colsum[f] * Wc[f * N_CLS + c];
        out[c] = acc / (float)n + bc[c];
    }
}

extern "C" void kernel_launch(void* const* d_in, const int* in_sizes, int n_in,
                              void* d_out, int out_size, void* d_ws, size_t ws_size,
                              hipStream_t stream) {
    const float* x   = (const float*)d_in[0];
    const int*   ei  = (const int*)d_in[1];
    const float* W1  = (const float*)d_in[2];
    const float* b1  = (const float*)d_in[3];
    const float* Ws1 = (const float*)d_in[4];
    const float* bs1 = (const float*)d_in[5];
    const float* W2  = (const float*)d_in[6];
    const float* b2  = (const float*)d_in[7];
    const float* Ws2 = (const float*)d_in[8];
    const float* bs2 = (const float*)d_in[9];
    const float* Wc  = (const float*)d_in[10];
    const float* bc  = (const float*)d_in[11];
    float* out = (float*)d_out;

    const int n = in_sizes[0] / FEAT;
    const int E = in_sizes[1] / 2;
    const int* src = ei;
    const int* dst = ei + E;

    const int nb = (n + 255) / 256;

    char* w = (char*)d_ws;
    auto alloc = [&](size_t bytes) -> void* {
        void* p = (void*)w;
        w += (bytes + 255) & ~(size_t)255;
        return p;
    };
    int*   deg    = (int*)alloc((size_t)n * 4);
    int*   off    = (int*)alloc(((size_t)n + 1) * 4);
    int*   csr    = (int*)alloc((size_t)E * 4);
    unsigned short* rank = (unsigned short*)alloc((size_t)E * 2);
    float* dinv   = (float*)alloc((size_t)n * 4);
    float* colsum = (float*)alloc(FEAT * 4);
    int*   bsum   = (int*)alloc((size_t)nb * 4);
    unsigned short* Wt1  = (unsigned short*)alloc(FEAT * FEAT * 2);
    unsigned short* Wst1 = (unsigned short*)alloc(FEAT * FEAT * 2);
    unsigned short* Wt2  = (unsigned short*)alloc(FEAT * FEAT * 2);
    unsigned short* Wst2 = (unsigned short*)alloc(FEAT * FEAT * 2);
    unsigned short* A = (unsigned short*)alloc((size_t)n * FEAT * 2);  // hs bf16
    float* B = (float*)alloc((size_t)n * FEAT * 4);  // xs1 -> out1
    float* C = (float*)alloc((size_t)n * FEAT * 4);  // xs2 -> out2

    // graph prep
    k_init<<<nb, 256, 0, stream>>>(deg, colsum, n);
    k_hist<<<(E + 255) / 256, 256, 0, stream>>>(dst, deg, rank, E);
    k_bsum<<<nb, 256, 0, stream>>>(deg, bsum, n);
    k_bscan<<<1, 256, 0, stream>>>(bsum, nb);
    k_write<<<nb, 256, 0, stream>>>(deg, bsum, off, dinv, n, E);
    k_fill<<<(E + 255) / 256, 256, 0, stream>>>(src, dst, rank, off, csr, E);

    // weight transposes (bf16, L2-resident)
    k_trans<<<64, 256, 0, stream>>>(W1, Wt1);
    k_trans<<<64, 256, 0, stream>>>(Ws1, Wst1);
    k_trans<<<64, 256, 0, stream>>>(W2, Wt2);
    k_trans<<<64, 256, 0, stream>>>(Ws2, Wst2);

    int gemm_grid = 2 * ((n + 63) / 64);
    int agg_grid  = (n + 7) / 8;

    // layer 1
    k_gemm<<<gemm_grid, 256, 0, stream>>>(x, Wt1, Wst1, b1, bs1, dinv, A, B, n);
    k_agg<<<agg_grid, 256, 0, stream>>>(A, B, dinv, off, csr, n);
    // layer 2
    k_gemm<<<gemm_grid, 256, 0, stream>>>(B, Wt2, Wst2, b2, bs2, dinv, A, C, n);
    k_agg<<<agg_grid, 256, 0, stream>>>(A, C, dinv, off, csr, n);

    // readout
    k_colsum<<<512, 256, 0, stream>>>(C, colsum, n);
    k_final<<<1, 64, 0, stream>>>(colsum, Wc, bc, out, n);
}

// Round 13
// 284.481 us; speedup vs baseline: 1.6983x; 1.0430x over previous
//
#include <hip/hip_runtime.h>

#define FEAT 128
#define N_CLS 10

typedef unsigned int uint;
typedef unsigned short ushort;
typedef __attribute__((ext_vector_type(8))) short short8v;  // 8 bf16 (4 VGPRs)
typedef __attribute__((ext_vector_type(4))) float f32x4;

// ---- bf16 helpers (manual, RNE pack / exact unpack) ----
__device__ inline ushort f2bf(float f) {
    union { float f; uint u; } c; c.f = f;
    uint r = (c.u + 0x7FFFu + ((c.u >> 16) & 1u)) >> 16;
    return (ushort)r;
}
__device__ inline float bfhi(uint u) {
    union { uint u; float f; } c; c.u = u & 0xFFFF0000u;
    return c.f;
}
__device__ inline float bflo(uint u) {
    union { uint u; float f; } c; c.u = u << 16;
    return c.f;
}

// ---------------- init: deg=0, colsum=0 ----------------
__global__ void k_init(int* deg, float* colsum, int n) {
    int i = blockIdx.x * blockDim.x + threadIdx.x;
    if (i < n) deg[i] = 0;
    if (i < FEAT) colsum[i] = 0.f;
}

// ---------------- histogram of dst + per-edge rank ----------------
__global__ void k_hist(const int* __restrict__ dst, int* deg,
                       ushort* __restrict__ rank, int E) {
    int e = blockIdx.x * blockDim.x + threadIdx.x;
    if (e < E) {
        int r = atomicAdd(&deg[dst[e]], 1);
        rank[e] = (ushort)r;
    }
}

// ---------------- hierarchical scan, stage 1 ----------------
__global__ __launch_bounds__(256) void k_bsum(const int* __restrict__ deg,
                                              int* __restrict__ bsum, int n) {
    int i = blockIdx.x * 256 + threadIdx.x;
    int v = (i < n) ? deg[i] : 0;
    #pragma unroll
    for (int d = 32; d; d >>= 1) v += __shfl_down(v, d, 64);
    __shared__ int ws[4];
    int lane = threadIdx.x & 63, wid = threadIdx.x >> 6;
    if (lane == 0) ws[wid] = v;
    __syncthreads();
    if (threadIdx.x == 0) bsum[blockIdx.x] = ws[0] + ws[1] + ws[2] + ws[3];
}

// ---------------- stage 2 ----------------
__global__ __launch_bounds__(256) void k_bscan(int* bsum, int nb) {
    __shared__ int lds[256];
    int t = threadIdx.x;
    int v = (t < nb) ? bsum[t] : 0;
    lds[t] = v;
    __syncthreads();
    #pragma unroll
    for (int d = 1; d < 256; d <<= 1) {
        int u = (t >= d) ? lds[t - d] : 0;
        __syncthreads();
        lds[t] += u;
        __syncthreads();
    }
    if (t < nb) bsum[t] = lds[t] - v;
}

// ---------------- stage 3: off/dinv ----------------
__global__ __launch_bounds__(256) void k_write(const int* __restrict__ deg,
                                               const int* __restrict__ bsum,
                                               int* off, float* dinv,
                                               int n, int E) {
    __shared__ int lds[256];
    int t = threadIdx.x;
    int i = blockIdx.x * 256 + t;
    int v = (i < n) ? deg[i] : 0;
    lds[t] = v;
    __syncthreads();
    #pragma unroll
    for (int d = 1; d < 256; d <<= 1) {
        int u = (t >= d) ? lds[t - d] : 0;
        __syncthreads();
        lds[t] += u;
        __syncthreads();
    }
    if (i < n) {
        off[i] = bsum[blockIdx.x] + (lds[t] - v);
        dinv[i] = rsqrtf((float)(deg[i] + 1));
    }
    if (i == n - 1) off[n] = E;
}

// ---------------- fill CSR (atomic-free) ----------------
__global__ void k_fill(const int* __restrict__ src, const int* __restrict__ dst,
                       const ushort* __restrict__ rank,
                       const int* __restrict__ off, int* __restrict__ csr, int E) {
    int e = blockIdx.x * blockDim.x + threadIdx.x;
    if (e < E) {
        int d = dst[e];
        csr[off[d] + (int)rank[e]] = src[e];
    }
}

// ---------------- transpose all 4 weights -> bf16 [col][k] (one dispatch) ----------------
__global__ __launch_bounds__(256) void k_trans4(
    const float* __restrict__ s0, const float* __restrict__ s1,
    const float* __restrict__ s2, const float* __restrict__ s3,
    ushort* __restrict__ d0, ushort* __restrict__ d1,
    ushort* __restrict__ d2, ushort* __restrict__ d3) {
    int m = blockIdx.x >> 6;           // 64 blocks per matrix
    int idx = (blockIdx.x & 63) * 256 + threadIdx.x;
    int c = idx >> 7, k = idx & 127;
    const float* s = (m == 0) ? s0 : (m == 1) ? s1 : (m == 2) ? s2 : s3;
    ushort* d = (m == 0) ? d0 : (m == 1) ? d1 : (m == 2) ? d2 : d3;
    d[c * FEAT + k] = f2bf(s[k * FEAT + c]);
}

// ---------------- MFMA split dual GEMM (col-sliced waves, hoisted W) ----------------
// BF16IN: 0 = fp32 input (layer1), 1 = bf16 input (layer2, no conversion)
template <int BF16IN>
__global__ __launch_bounds__(256) void k_gemm(
    const void* __restrict__ xin, const ushort* __restrict__ Wt,
    const ushort* __restrict__ Wst, const float* __restrict__ b,
    const float* __restrict__ bs, const float* __restrict__ dinv,
    ushort* __restrict__ hs, float* __restrict__ xs, int n) {
    __shared__ ushort x_lds[64 * 136];  // +8 bf16 pad
    int tid = threadIdx.x;
    int pair = blockIdx.x >> 1;
    int which = blockIdx.x & 1;
    int row0 = pair * 64;

    // stage x tile -> bf16 LDS
    int c4 = (tid & 31) * 4;
    int rl = tid >> 5;
    #pragma unroll
    for (int p = 0; p < 8; ++p) {
        int r = rl + p * 8;
        uint2 pk = make_uint2(0u, 0u);
        if (row0 + r < n) {
            if (BF16IN) {
                pk = *(const uint2*)&((const ushort*)xin)[(size_t)(row0 + r) * FEAT + c4];
            } else {
                float4 v = *(const float4*)&((const float*)xin)[(size_t)(row0 + r) * FEAT + c4];
                pk.x = (uint)f2bf(v.x) | ((uint)f2bf(v.y) << 16);
                pk.y = (uint)f2bf(v.z) | ((uint)f2bf(v.w) << 16);
            }
        }
        *(uint2*)&x_lds[r * 136 + c4] = pk;
    }

    int wv = tid >> 6;        // wave -> col-tiles {2wv, 2wv+1}
    int lane = tid & 63;
    int lr = lane & 15;
    int lg = lane >> 4;
    int ctb = wv * 2;

    // hoist W fragments (8 loads, reused 4x)
    const ushort* Wp = which ? Wst : Wt;
    short8v wf[2][4];
    #pragma unroll
    for (int c = 0; c < 2; ++c)
        #pragma unroll
        for (int ks = 0; ks < 4; ++ks)
            wf[c][ks] = *(const short8v*)&Wp[(size_t)((ctb + c) * 16 + lr) * FEAT + ks * 32 + lg * 8];

    float4 bias[2];
    #pragma unroll
    for (int c = 0; c < 2; ++c) {
        int col = (ctb + c) * 16 + lg * 4;
        float4 bb  = *(const float4*)&b[col];
        float4 bb2 = *(const float4*)&bs[col];
        bias[c] = make_float4(bb.x + bb2.x, bb.y + bb2.y, bb.z + bb2.z, bb.w + bb2.w);
    }

    __syncthreads();

    #pragma unroll
    for (int ng = 0; ng < 4; ++ng) {
        short8v a[4];
        #pragma unroll
        for (int ks = 0; ks < 4; ++ks)
            a[ks] = *(const short8v*)&x_lds[(ng * 16 + lr) * 136 + ks * 32 + lg * 8];

        f32x4 acc[2];
        acc[0] = (f32x4){0.f, 0.f, 0.f, 0.f};
        acc[1] = (f32x4){0.f, 0.f, 0.f, 0.f};
        #pragma unroll
        for (int ks = 0; ks < 4; ++ks) {
            acc[0] = __builtin_amdgcn_mfma_f32_16x16x32_bf16(wf[0][ks], a[ks], acc[0], 0, 0, 0);
            acc[1] = __builtin_amdgcn_mfma_f32_16x16x32_bf16(wf[1][ks], a[ks], acc[1], 0, 0, 0);
        }

        int node = row0 + ng * 16 + lr;
        if (node < n) {
            if (which == 0) {
                float dv = dinv[node];
                #pragma unroll
                for (int c = 0; c < 2; ++c) {
                    int col = (ctb + c) * 16 + lg * 4;
                    uint2 pk;
                    pk.x = (uint)f2bf(acc[c][0] * dv) | ((uint)f2bf(acc[c][1] * dv) << 16);
                    pk.y = (uint)f2bf(acc[c][2] * dv) | ((uint)f2bf(acc[c][3] * dv) << 16);
                    *(uint2*)&hs[(size_t)node * FEAT + col] = pk;
                }
            } else {
                #pragma unroll
                for (int c = 0; c < 2; ++c) {
                    int col = (ctb + c) * 16 + lg * 4;
                    float4 o = make_float4(acc[c][0] + bias[c].x, acc[c][1] + bias[c].y,
                                           acc[c][2] + bias[c].z, acc[c][3] + bias[c].w);
                    *(float4*)&xs[(size_t)node * FEAT + col] = o;
                }
            }
        }
    }
}

// ---------------- aggregation + skip + relu ----------------
// MODE 0: write bf16 rows to outb (layer1 -> gemm2 input)
// MODE 1: no row output; per-block colsum partials to psum[block][128] (layer2)
template <int MODE>
__global__ __launch_bounds__(256) void k_agg(
    const ushort* __restrict__ hs, const float* __restrict__ xs,
    ushort* __restrict__ outb, float* __restrict__ psum,
    const float* __restrict__ dinv, const int* __restrict__ off,
    const int* __restrict__ csr, int n) {
    int tid = threadIdx.x;
    int node = (blockIdx.x * 256 + tid) >> 5;
    int sub = tid & 31;
    bool alive = node < n;
    float4 out = make_float4(0.f, 0.f, 0.f, 0.f);
    size_t fo = (size_t)sub * 4;
    if (alive) {
        const uint2* hp = (const uint2*)&hs[(size_t)node * FEAT + fo];
        uint2 p = *hp;  // self loop (pre-scaled)
        float4 a0 = make_float4(bflo(p.x), bfhi(p.x), bflo(p.y), bfhi(p.y));
        float4 a1 = make_float4(0.f, 0.f, 0.f, 0.f);
        float4 a2 = make_float4(0.f, 0.f, 0.f, 0.f);
        float4 a3 = make_float4(0.f, 0.f, 0.f, 0.f);
        int s = off[node], e = off[node + 1];
        int j = s;
        for (; j + 4 <= e; j += 4) {
            int u0 = csr[j], u1 = csr[j + 1], u2 = csr[j + 2], u3 = csr[j + 3];
            uint2 q0 = *(const uint2*)&hs[(size_t)u0 * FEAT + fo];
            uint2 q1 = *(const uint2*)&hs[(size_t)u1 * FEAT + fo];
            uint2 q2 = *(const uint2*)&hs[(size_t)u2 * FEAT + fo];
            uint2 q3 = *(const uint2*)&hs[(size_t)u3 * FEAT + fo];
            a0.x += bflo(q0.x); a0.y += bfhi(q0.x); a0.z += bflo(q0.y); a0.w += bfhi(q0.y);
            a1.x += bflo(q1.x); a1.y += bfhi(q1.x); a1.z += bflo(q1.y); a1.w += bfhi(q1.y);
            a2.x += bflo(q2.x); a2.y += bfhi(q2.x); a2.z += bflo(q2.y); a2.w += bfhi(q2.y);
            a3.x += bflo(q3.x); a3.y += bfhi(q3.x); a3.z += bflo(q3.y); a3.w += bfhi(q3.y);
        }
        for (; j < e; ++j) {
            int u = csr[j];
            uint2 q = *(const uint2*)&hs[(size_t)u * FEAT + fo];
            a0.x += bflo(q.x); a0.y += bfhi(q.x); a0.z += bflo(q.y); a0.w += bfhi(q.y);
        }
        float4 acc;
        acc.x = (a0.x + a1.x) + (a2.x + a3.x);
        acc.y = (a0.y + a1.y) + (a2.y + a3.y);
        acc.z = (a0.z + a1.z) + (a2.z + a3.z);
        acc.w = (a0.w + a1.w) + (a2.w + a3.w);
        float dv = dinv[node];
        float4 sk = *(const float4*)&xs[(size_t)node * FEAT + fo];
        out.x = fmaxf(fmaf(acc.x, dv, sk.x), 0.f);
        out.y = fmaxf(fmaf(acc.y, dv, sk.y), 0.f);
        out.z = fmaxf(fmaf(acc.z, dv, sk.z), 0.f);
        out.w = fmaxf(fmaf(acc.w, dv, sk.w), 0.f);
    }
    if (MODE == 0) {
        if (alive) {
            uint2 pk;
            pk.x = (uint)f2bf(out.x) | ((uint)f2bf(out.y) << 16);
            pk.y = (uint)f2bf(out.z) | ((uint)f2bf(out.w) << 16);
            *(uint2*)&outb[(size_t)node * FEAT + fo] = pk;
        }
    } else {
        __shared__ float sacc[8][FEAT];
        int hw = tid >> 5;  // half-wave 0..7
        *(float4*)&sacc[hw][sub * 4] = out;
        __syncthreads();
        if (tid < FEAT) {
            float s = 0.f;
            #pragma unroll
            for (int h = 0; h < 8; ++h) s += sacc[h][tid];
            psum[(size_t)blockIdx.x * FEAT + tid] = s;
        }
    }
}

// ---------------- column sum over [rows][128] -> colsum (atomics on 128 addrs) ----------------
__global__ __launch_bounds__(256) void k_colsum(const float* __restrict__ x2,
                                                float* colsum, int n) {
    __shared__ float lds[256];
    int tid = threadIdx.x;
    int f = tid & 127;
    int half = tid >> 7;
    float acc = 0.f;
    for (int r = blockIdx.x * 2 + half; r < n; r += gridDim.x * 2)
        acc += x2[(size_t)r * FEAT + f];
    lds[tid] = acc;
    __syncthreads();
    if (tid < 128) atomicAdd(&colsum[f], lds[f] + lds[f + 128]);
}

// ---------------- final: (colsum/n) @ Wc + bc ----------------
__global__ void k_final(const float* __restrict__ colsum, const float* __restrict__ Wc,
                        const float* __restrict__ bc, float* out, int n) {
    int c = threadIdx.x;
    if (c < N_CLS) {
        float acc = 0.f;
        for (int f = 0; f < FEAT; ++f) acc += colsum[f] * Wc[f * N_CLS + c];
        out[c] = acc / (float)n + bc[c];
    }
}

extern "C" void kernel_launch(void* const* d_in, const int* in_sizes, int n_in,
                              void* d_out, int out_size, void* d_ws, size_t ws_size,
                              hipStream_t stream) {
    const float* x   = (const float*)d_in[0];
    const int*   ei  = (const int*)d_in[1];
    const float* W1  = (const float*)d_in[2];
    const float* b1  = (const float*)d_in[3];
    const float* Ws1 = (const float*)d_in[4];
    const float* bs1 = (const float*)d_in[5];
    const float* W2  = (const float*)d_in[6];
    const float* b2  = (const float*)d_in[7];
    const float* Ws2 = (const float*)d_in[8];
    const float* bs2 = (const float*)d_in[9];
    const float* Wc  = (const float*)d_in[10];
    const float* bc  = (const float*)d_in[11];
    float* out = (float*)d_out;

    const int n = in_sizes[0] / FEAT;
    const int E = in_sizes[1] / 2;
    const int* src = ei;
    const int* dst = ei + E;

    const int nb = (n + 255) / 256;
    const int agg_grid = (n + 7) / 8;

    char* w = (char*)d_ws;
    auto alloc = [&](size_t bytes) -> void* {
        void* p = (void*)w;
        w += (bytes + 255) & ~(size_t)255;
        return p;
    };
    int*   deg    = (int*)alloc((size_t)n * 4);
    int*   off    = (int*)alloc(((size_t)n + 1) * 4);
    int*   csr    = (int*)alloc((size_t)E * 4);
    ushort* rank  = (ushort*)alloc((size_t)E * 2);
    float* dinv   = (float*)alloc((size_t)n * 4);
    float* colsum = (float*)alloc(FEAT * 4);
    int*   bsum   = (int*)alloc((size_t)nb * 4);
    float* psum   = (float*)alloc((size_t)agg_grid * FEAT * 4);
    ushort* Wt1  = (ushort*)alloc(FEAT * FEAT * 2);
    ushort* Wst1 = (ushort*)alloc(FEAT * FEAT * 2);
    ushort* Wt2  = (ushort*)alloc(FEAT * FEAT * 2);
    ushort* Wst2 = (ushort*)alloc(FEAT * FEAT * 2);
    ushort* A = (ushort*)alloc((size_t)n * FEAT * 2);  // hs bf16 (both layers)
    float*  B = (float*)alloc((size_t)n * FEAT * 4);   // xs1 fp32
    float*  C = (float*)alloc((size_t)n * FEAT * 4);   // xs2 fp32
    ushort* D = (ushort*)alloc((size_t)n * FEAT * 2);  // out1 bf16 (layer2 input)

    // graph prep
    k_init<<<nb, 256, 0, stream>>>(deg, colsum, n);
    k_hist<<<(E + 255) / 256, 256, 0, stream>>>(dst, deg, rank, E);
    k_bsum<<<nb, 256, 0, stream>>>(deg, bsum, n);
    k_bscan<<<1, 256, 0, stream>>>(bsum, nb);
    k_write<<<nb, 256, 0, stream>>>(deg, bsum, off, dinv, n, E);
    k_fill<<<(E + 255) / 256, 256, 0, stream>>>(src, dst, rank, off, csr, E);
    k_trans4<<<256, 256, 0, stream>>>(W1, Ws1, W2, Ws2, Wt1, Wst1, Wt2, Wst2);

    int gemm_grid = 2 * ((n + 63) / 64);

    // layer 1
    k_gemm<0><<<gemm_grid, 256, 0, stream>>>(x, Wt1, Wst1, b1, bs1, dinv, A, B, n);
    k_agg<0><<<agg_grid, 256, 0, stream>>>(A, B, D, nullptr, dinv, off, csr, n);
    // layer 2 (bf16 input D; readout fused into agg)
    k_gemm<1><<<gemm_grid, 256, 0, stream>>>(D, Wt2, Wst2, b2, bs2, dinv, A, C, n);
    k_agg<1><<<agg_grid, 256, 0, stream>>>(A, C, nullptr, psum, dinv, off, csr, n);

    // readout
    k_colsum<<<512, 256, 0, stream>>>(psum, colsum, agg_grid);
    k_final<<<1, 64, 0, stream>>>(colsum, Wc, bc, out, n);
}